// Round 6
// baseline (246.196 us; speedup 1.0000x reference)
//
#include <hip/hip_runtime.h>

// RouterAttention on gfx950. B=4 L=S=4096 D=512 H=8 E=R=64.
// R9/R10: scheduling variants NEUTRAL (barrier drains; XCD swizzle kept).
// R11: router_v rework NEUTRAL. R12: tile-chaining REGRESSED (epilogue inside
// barrier region + 2 blk/CU) — reverted.
// R13: cut the largest serial pipe term (LDS ~27us/CU): A-operand streams
// global->VGPR (L1-hot, no LDS, no barrier dep); B-only LDS dbuf 2x16KB;
// stage(t+1) before compute(t); ONE barrier per K-step (8 vs 16).

#define DEV __device__ __forceinline__
#define SCHED_FENCE() __builtin_amdgcn_sched_barrier(0)

constexpr int Bn = 4, Ln = 4096, Dn = 512, Hn = 8, En = 64, Rn = 64;
constexpr int Sn = 4096;
constexpr float SCALE = 0.125f;                 // 1/sqrt(E)
constexpr float L2B_OVER_K = 13.287712379549449f / 32.0f; // log2(10000)/32

typedef __bf16 bf16x8 __attribute__((ext_vector_type(8)));
typedef float floatx4 __attribute__((ext_vector_type(4)));

DEV float bf2f(ushort u) { return __uint_as_float(((unsigned)u) << 16); }
DEV ushort f2bf(float f) {
    unsigned u = __float_as_uint(f);
    u += 0x7fffu + ((u >> 16) & 1u);            // RNE
    return (ushort)(u >> 16);
}
DEV bf16x8 ldsfrag(const ushort* p) { return *reinterpret_cast<const bf16x8*>(p); }
#define MFMA(a, b, c) __builtin_amdgcn_mfma_f32_16x16x32_bf16(a, b, c, 0, 0, 0)

DEV void gload16(const ushort* g, ushort* lds) {
    __builtin_amdgcn_global_load_lds(
        (const __attribute__((address_space(1))) unsigned int*)g,
        (__attribute__((address_space(3))) unsigned int*)lds, 16, 0, 0);
}

DEV int wave_sum_i(int v) {
    #pragma unroll
    for (int off = 1; off < 64; off <<= 1) v += __shfl_xor(v, off);
    return v;
}

// ---- dtype sniffer (fallback only): flag=1 if x looks like f32 ----
__global__ __launch_bounds__(256) void sniff_k(const uint* __restrict__ x, int* __restrict__ flag) {
    int t = threadIdx.x, cnt = 0;
    #pragma unroll
    for (int i = 0; i < 16; ++i) {
        uint u = x[t * 16 + i];
        uint e = (u >> 7) & 0xFF;
        cnt += (e >= 100 && e <= 140) ? 1 : 0;
    }
    cnt = wave_sum_i(cnt);
    __shared__ int red[4];
    int w = t >> 6, l = t & 63;
    if (l == 0) red[w] = cnt;
    __syncthreads();
    if (t == 0) flag[0] = ((red[0] + red[1] + red[2] + red[3]) < 2048) ? 1 : 0;
}

constexpr size_t SEG1 = 8388608, SEG2 = 8650752, SEG3 = 8651264, SEG4 = 8913408,
                 SEG5 = 8913920, SEG6 = 9176064, SEG7 = 9176576, SEG8 = 9438720,
                 SEG9 = 9439232, SEGT = 9472000;

// ---- prep0: canon vec8 (4625 blk) + rope tabs (512 blk) + zero (131 blk) ----
__global__ __launch_bounds__(256)
void prep0_k(const void* p0, const void* p1, const void* p2, const void* p3,
             const void* p4, const void* p5, const void* p6, const void* p7,
             const void* p8, const void* p9, const int* __restrict__ flag,
             int fhost,
             ushort* __restrict__ dst, float2* __restrict__ tab_pj,
             float2* __restrict__ tab_jp, float* __restrict__ rV,
             float* __restrict__ lsum) {
    const int bid = blockIdx.x, tid = threadIdx.x;
    if (bid < 4625) {                           // canon: 8 elems/thread
        const int f = (fhost >= 0) ? fhost : *flag;
        size_t i = ((size_t)bid * 256 + tid) * 8;   // all SEG bounds %8==0
        const void* sp; size_t off;
        if      (i < SEG1) { sp = p0; off = i; }
        else if (i < SEG2) { sp = p1; off = i - SEG1; }
        else if (i < SEG3) { sp = p2; off = i - SEG2; }
        else if (i < SEG4) { sp = p3; off = i - SEG3; }
        else if (i < SEG5) { sp = p4; off = i - SEG4; }
        else if (i < SEG6) { sp = p5; off = i - SEG5; }
        else if (i < SEG7) { sp = p6; off = i - SEG6; }
        else if (i < SEG8) { sp = p7; off = i - SEG7; }
        else if (i < SEG9) { sp = p8; off = i - SEG8; }
        else               { sp = p9; off = i - SEG9; }
        ushort o8[8];
        if (f) {
            float4 a = *((const float4*)((const float*)sp + off));
            float4 b = *((const float4*)((const float*)sp + off) + 1);
            o8[0] = f2bf(a.x); o8[1] = f2bf(a.y); o8[2] = f2bf(a.z); o8[3] = f2bf(a.w);
            o8[4] = f2bf(b.x); o8[5] = f2bf(b.y); o8[6] = f2bf(b.z); o8[7] = f2bf(b.w);
        } else {
            *(uint4*)o8 = *(const uint4*)((const ushort*)sp + off);
        }
        *(uint4*)&dst[i] = *(uint4*)o8;
    } else if (bid < 5137) {                    // rope tables (both layouts)
        int idx = (bid - 4625) * 256 + tid;     // 131072 entries
        int p = idx >> 5, j = idx & 31;
        float theta = exp2f(-(float)j * L2B_OVER_K);
        float ang = (float)(Sn - 1 - p) * theta;
        float s, c;
        sincosf(ang, &s, &c);
        tab_pj[idx] = make_float2(c, s);
        tab_jp[j * Sn + p] = make_float2(c, s);
    } else {                                    // zero rV + lsum
        int base = (bid - 5137) * 1024 + tid;
        #pragma unroll
        for (int r = 0; r < 4; ++r) {
            int f32i = base + r * 256;
            if (f32i < 131072) rV[f32i] = 0.f;
            else if (f32i < 133120) lsum[f32i - 131072] = 0.f;
        }
    }
}

// ---- prep1: 2 transposes (128 blk) + prep_wr (128 blk) + prep_bias (1 blk) ----
__global__ __launch_bounds__(256)
void prep1_k(const ushort* __restrict__ Wskc, const ushort* __restrict__ Wzc,
             const ushort* __restrict__ Wqc, const ushort* __restrict__ Wkc,
             const ushort* __restrict__ RPc, const ushort* __restrict__ bqc,
             const ushort* __restrict__ bskc, const ushort* __restrict__ bzc,
             ushort* __restrict__ Wtcat, ushort* __restrict__ Wkr,
             float* __restrict__ biascat) {
    __shared__ ushort t64[64][65];
    __shared__ ushort As1[64][72];
    __shared__ ushort Bs1[64][72];
    const int bid = blockIdx.x, tid = threadIdx.x;
    if (bid < 128) {                            // transpose: Wt[dout][din]
        const ushort* W = (bid < 64) ? Wskc : Wzc;
        ushort* Wt = Wtcat + (bid < 64 ? 0 : 262144);
        int bb = bid & 63;
        int bx = (bb & 7) * 64, by = (bb >> 3) * 64;
        int c = tid & 63, r0 = (tid >> 6) * 16;
        #pragma unroll
        for (int i = 0; i < 16; ++i) t64[r0 + i][c] = W[(size_t)(by + r0 + i) * Dn + bx + c];
        __syncthreads();
        #pragma unroll
        for (int i = 0; i < 16; ++i) Wt[(size_t)(bx + r0 + i) * Dn + by + c] = t64[c][r0 + i];
    } else if (bid < 256) {                     // prep_wr
        int idx = bid - 128;
        int zsel = idx >> 6, rem = idx & 63;
        int d0 = (rem & 7) * 64, h = rem >> 3;
        const ushort* W = zsel ? Wkc : Wqc;
        ushort* Out = zsel ? Wkr : (Wtcat + 524288);
        #pragma unroll
        for (int j = 0; j < 2; ++j) {
            int lin = j * 256 + tid, row = lin >> 3, c = (lin & 7) * 8;
            *(uint4*)&As1[row][c] = *(const uint4*)&RPc[(size_t)row * Dn + h * En + c];
            *(uint4*)&Bs1[row][c] = *(const uint4*)&W[(size_t)(d0 + row) * Dn + h * En + c];
        }
        __syncthreads();
        const int w = tid >> 6, l = tid & 63;
        const int mt = (w >> 1) * 32, nt = (w & 1) * 32, lr = l & 15, lq = l >> 4;
        floatx4 acc[2][2] = {};
        #pragma unroll
        for (int ks = 0; ks < 64; ks += 32) {
            bf16x8 a0 = ldsfrag(&As1[mt + lr][ks + lq * 8]);
            bf16x8 a1 = ldsfrag(&As1[mt + 16 + lr][ks + lq * 8]);
            bf16x8 b0 = ldsfrag(&Bs1[nt + lr][ks + lq * 8]);
            bf16x8 b1 = ldsfrag(&Bs1[nt + 16 + lr][ks + lq * 8]);
            acc[0][0] = MFMA(a0, b0, acc[0][0]);
            acc[0][1] = MFMA(a0, b1, acc[0][1]);
            acc[1][0] = MFMA(a1, b0, acc[1][0]);
            acc[1][1] = MFMA(a1, b1, acc[1][1]);
        }
        #pragma unroll
        for (int mi = 0; mi < 2; ++mi)
            #pragma unroll
            for (int ni = 0; ni < 2; ++ni)
                #pragma unroll
                for (int ri = 0; ri < 4; ++ri) {
                    int ro = mt + mi * 16 + lq * 4 + ri;
                    int d = d0 + nt + ni * 16 + lr;
                    Out[(size_t)(h * En + ro) * Dn + d] = f2bf(acc[mi][ni][ri] * SCALE);
                }
    } else {                                    // prep_bias
        #pragma unroll
        for (int it = 0; it < 2; ++it) {
            int i = it * 256 + tid;
            biascat[i]       = bf2f(bskc[i]);
            biascat[512 + i] = bf2f(bzc[i]);
            int h = i >> 6, ro = i & 63;
            float s = 0.f;
            for (int e = 0; e < 64; ++e)
                s += bf2f(bqc[h * En + e]) * bf2f(RPc[(size_t)ro * Dn + h * En + e]);
            biascat[1024 + i] = s * SCALE;
        }
    }
}

// ---- B-only staging (16 KB/step), conflict-free swizzle ----
DEV void stageB(const ushort* __restrict__ Bg, int n0, int kc,
                ushort* Bs, int w, int l) {
    #pragma unroll
    for (int j = 0; j < 4; ++j) {
        int slot = (w * 4 + j) * 64 + l;        // 0..1023 (x16B = 16 KB)
        int row = slot >> 3;
        int c = ((slot & 7) - row) & 7;
        gload16(&Bg[(size_t)(n0 + row) * Dn + kc + c * 8], &Bs[(w * 4 + j) * 512]);
    }
}

// ---- compute: A direct global->VGPR (L1-hot), B from swizzled LDS ----
DEV void computeRA(const ushort* __restrict__ Ag, int m0, int kc,
                   const ushort* Bs, int mt, int nt, int lr, int lq,
                   floatx4 (&acc)[4][4]) {
    #pragma unroll
    for (int ks = 0; ks < 64; ks += 32) {
        bf16x8 a[4], bb[4];
        const int cc = (ks >> 3) + lq;
        #pragma unroll
        for (int i = 0; i < 4; ++i)
            a[i] = *(const bf16x8*)&Ag[(size_t)(m0 + mt + 16 * i + lr) * Dn
                                       + kc + ks + lq * 8];
        #pragma unroll
        for (int i = 0; i < 4; ++i) {
            int row = nt + 16 * i + lr;
            bb[i] = ldsfrag(&Bs[(row * 8 + ((cc + row) & 7)) * 8]);
        }
        #pragma unroll
        for (int mi = 0; mi < 4; ++mi)
            #pragma unroll
            for (int ni = 0; ni < 4; ++ni)
                acc[mi][ni] = MFMA(a[mi], bb[ni], acc[mi][ni]);
    }
}

// K-loop: B dbuf 2x16KB; stage(t+1) issued BEFORE compute(t) so the 4
// global_load_lds hide under ~600cy of MFMA; ONE barrier per K-step.
// Race check: stage(t+1) writes buf[(t+1)&1] whose last readers (compute t-1)
// all passed barrier(t-1); compute(t) reads buf[t&1]; vmcnt(0)+lgkm(0)+barrier
// then publishes buf[(t+1)&1] and frees buf[t&1] for stage(t+2).
DEV void kloop128(const ushort* __restrict__ Ag, const ushort* __restrict__ Bg,
                  int m0, int n0, ushort* Bs, int tid, floatx4 (&acc)[4][4]) {
    const int w = tid >> 6, l = tid & 63;
    const int mt = (w >> 1) * 64, nt = (w & 1) * 64;
    const int lr = l & 15, lq = l >> 4;
    stageB(Bg, n0, 0, Bs, w, l);
    asm volatile("s_waitcnt vmcnt(0)" ::: "memory");
    SCHED_FENCE();
    __builtin_amdgcn_s_barrier();
    SCHED_FENCE();
    #pragma unroll
    for (int t = 0; t < 8; ++t) {
        if (t < 7)
            stageB(Bg, n0, (t + 1) * 64, Bs + ((t + 1) & 1) * 8192, w, l);
        computeRA(Ag, m0, t * 64, Bs + (t & 1) * 8192, mt, nt, lr, lq, acc);
        asm volatile("s_waitcnt lgkmcnt(0)" ::: "memory");
        SCHED_FENCE();
        asm volatile("s_waitcnt vmcnt(0)" ::: "memory");   // stage(t+1) landed
        SCHED_FENCE();
        __builtin_amdgcn_s_barrier();
        SCHED_FENCE();
    }
}

// ---- big_k: proj (1536) + rscore (512), XCD-chunk swizzled (2048 = 8*256) ----
__global__ __launch_bounds__(256)
void big_k(const ushort* __restrict__ X, const ushort* __restrict__ Wtcat,
           const float* __restrict__ biascat, const ushort* __restrict__ Wkr,
           ushort* __restrict__ skip, ushort* __restrict__ z,
           ushort* __restrict__ qs, ushort* __restrict__ E,
           float* __restrict__ lsum) {
    __shared__ __align__(16) ushort Bs[16384]; // 2 x 16KB B double-buffer
    const int bid = blockIdx.x, tid = threadIdx.x;
    const int w = tid >> 6, l = tid & 63;
    const int mt = (w >> 1) * 64, nt = (w & 1) * 64;
    const int lr = l & 15, lq = l >> 4;
    const int swz = (bid & 7) * 256 + (bid >> 3);   // bijective XCD swizzle
    floatx4 acc[4][4] = {};
    if (swz < 1536) {                           // ---- projection GEMM ----
        const int n0 = (swz % 12) * 128;
        const int m0 = (swz / 12) * 128;
        kloop128(X, Wtcat, m0, n0, Bs, tid, acc);
        const int sec = n0 >> 9;                // 0=skip 1=z 2=qs
        ushort* dst = sec == 0 ? skip : (sec == 1 ? z : qs);
        #pragma unroll
        for (int ni = 0; ni < 4; ++ni) {
            int ng = n0 + nt + ni * 16 + lr;
            float bbv = biascat[ng];
            int nc = ng & 511;
            #pragma unroll
            for (int mi = 0; mi < 4; ++mi)
                #pragma unroll
                for (int ri = 0; ri < 4; ++ri) {
                    int row = m0 + mt + mi * 16 + lq * 4 + ri;
                    float v = acc[mi][ni][ri] + bbv;
                    if (sec == 1) v = v / (1.0f + __expf(-v));
                    dst[(size_t)row * Dn + nc] = f2bf(v);
                }
        }
    } else {                                    // ---- router scores GEMM ----
        int idx = swz - 1536;                   // 0..511
        const int n0 = (idx & 127) * 128;       // x row = b*4096+s
        const int m0 = (idx >> 7) * 128;        // Wkr row = h*64+r
        kloop128(Wkr, X, m0, n0, Bs, tid, acc);
        const int b = n0 >> 12;
        const int sbase = (n0 & 4095) + nt;
        #pragma unroll
        for (int mi = 0; mi < 4; ++mi)
            #pragma unroll
            for (int ri = 0; ri < 4; ++ri) {
                size_t row = (size_t)(b * 512 + m0 + mt + mi * 16 + lq * 4 + ri);
                float rs = 0.f;
                #pragma unroll
                for (int ni = 0; ni < 4; ++ni) {
                    int s = sbase + ni * 16 + lr;
                    float e = __expf(acc[mi][ni][ri]);
                    E[row * Sn + s] = f2bf(e);
                    rs += e;
                }
                rs += __shfl_xor(rs, 1); rs += __shfl_xor(rs, 2);
                rs += __shfl_xor(rs, 4); rs += __shfl_xor(rs, 8);
                if (lr == 0) atomicAdd(&lsum[row], rs);
            }
    }
}

// ---- rV[bh][r][e] += sum_s rope(E/l)[r][s] * v[s][e]; 2 chunks/block ----
__global__ __launch_bounds__(256)
void router_v_k(const ushort* __restrict__ E, const float* __restrict__ lsum,
                const ushort* __restrict__ X, const float2* __restrict__ tab_jp,
                float* __restrict__ rV) {
    __shared__ ushort As[64][136];   // rope(E/l)[r][s0..127]
    __shared__ ushort Bs[64][136];   // v^T[e][s]
    __shared__ float invl[64];
    const int tid = threadIdx.x;
    const int bh = blockIdx.y, b = bh >> 3, h = bh & 7;
    const int s0 = blockIdx.x * 256;
    const int w = tid >> 6, l = tid & 63;
    const int mt = (w >> 1) * 32, nt = (w & 1) * 32, lr = l & 15, lq = l >> 4;
    if (tid < 64) invl[tid] = 1.0f / lsum[(size_t)bh * Rn + tid];
    __syncthreads();
    floatx4 acc[2][2] = {};
    for (int c = 0; c < 2; ++c) {
        const int sb = s0 + c * 128;
        if (c) __syncthreads();                 // all waves done with chunk c-1
        #pragma unroll
        for (int it = 0; it < 4; ++it) {        // rope staging: 4 s per thread
            int lin = it * 256 + tid;
            int j = lin >> 5, sq = (lin & 31) * 4, sg = sb + sq;
            const ushort* ep = &E[((size_t)bh * Rn + 2 * j) * Sn + sg];
            uint2 ue = *(const uint2*)ep;
            uint2 uo = *(const uint2*)(ep + Sn);
            float4 t01 = *(const float4*)&tab_jp[(size_t)j * Sn + sg];
            float4 t23 = *(const float4*)&tab_jp[(size_t)j * Sn + sg + 2];
            float il_e = invl[2 * j], il_o = invl[2 * j + 1];
            float pe0 = bf2f((ushort)(ue.x & 0xffff)) * il_e;
            float pe1 = bf2f((ushort)(ue.x >> 16)) * il_e;
            float pe2 = bf2f((ushort)(ue.y & 0xffff)) * il_e;
            float pe3 = bf2f((ushort)(ue.y >> 16)) * il_e;
            float po0 = bf2f((ushort)(uo.x & 0xffff)) * il_o;
            float po1 = bf2f((ushort)(uo.x >> 16)) * il_o;
            float po2 = bf2f((ushort)(uo.y & 0xffff)) * il_o;
            float po3 = bf2f((ushort)(uo.y >> 16)) * il_o;
            ushort re[4], ro[4];
            re[0] = f2bf(pe0 * t01.x - po0 * t01.y);
            ro[0] = f2bf(pe0 * t01.y + po0 * t01.x);
            re[1] = f2bf(pe1 * t01.z - po1 * t01.w);
            ro[1] = f2bf(pe1 * t01.w + po1 * t01.z);
            re[2] = f2bf(pe2 * t23.x - po2 * t23.y);
            ro[2] = f2bf(pe2 * t23.y + po2 * t23.x);
            re[3] = f2bf(pe3 * t23.z - po3 * t23.w);
            ro[3] = f2bf(pe3 * t23.w + po3 * t23.z);
            *(uint2*)&As[2 * j][sq]     = *(uint2*)re;
            *(uint2*)&As[2 * j + 1][sq] = *(uint2*)ro;
        }
        #pragma unroll
        for (int it = 0; it < 4; ++it) {        // v^T staging, uint4 loads
            int lin = it * 256 + tid;
            int s = lin >> 3, eg = (lin & 7) * 8;
            ushort u8[8];
            *(uint4*)u8 = *(const uint4*)&X[(size_t)(b * Ln + sb + s) * Dn + h * En + eg];
            #pragma unroll
            for (int t = 0; t < 8; ++t) Bs[eg + t][s] = u8[t];
        }
        __syncthreads();
        #pragma unroll
        for (int ks = 0; ks < 128; ks += 32) {
            bf16x8 a0 = ldsfrag(&As[mt + lr][ks + lq * 8]);
            bf16x8 a1 = ldsfrag(&As[mt + 16 + lr][ks + lq * 8]);
            bf16x8 b0 = ldsfrag(&Bs[nt + lr][ks + lq * 8]);
            bf16x8 b1 = ldsfrag(&Bs[nt + 16 + lr][ks + lq * 8]);
            acc[0][0] = MFMA(a0, b0, acc[0][0]);
            acc[0][1] = MFMA(a0, b1, acc[0][1]);
            acc[1][0] = MFMA(a1, b0, acc[1][0]);
            acc[1][1] = MFMA(a1, b1, acc[1][1]);
        }
    }
    #pragma unroll
    for (int mi = 0; mi < 2; ++mi)
        #pragma unroll
        for (int ni = 0; ni < 2; ++ni)
            #pragma unroll
            for (int ri = 0; ri < 4; ++ri) {
                int r = mt + mi * 16 + lq * 4 + ri;
                int e = nt + ni * 16 + lr;
                atomicAdd(&rV[((size_t)bh * Rn + r) * En + e], acc[mi][ni][ri]);
            }
}

// ---- fused query path: qs -> in-thread softmax -> rope -> @rV -> (+skip)*z ----
__global__ __launch_bounds__(256)
void final_attn_k(const ushort* __restrict__ QS, const float* __restrict__ rV,
                  const float2* __restrict__ tab_pj, const ushort* __restrict__ Skip,
                  const ushort* __restrict__ Zs, const int* __restrict__ flagp,
                  int fhost, void* __restrict__ Outv) {
    __shared__ ushort Ap[64][72];
    __shared__ ushort BvT[64][72];
    __shared__ float Cs[64][68];
    const int f = (fhost >= 0) ? fhost : *flagp;
    const int tid = threadIdx.x;
    const int h = blockIdx.y, b = blockIdx.z, bh = b * Hn + h;
    const int l0 = blockIdx.x * 64;
    const int w = tid >> 6, l = tid & 63;
    const int mt = (w >> 1) * 32, nt = (w & 1) * 32, lr = l & 15, lq = l >> 4;
    #pragma unroll
    for (int i = 0; i < 16; ++i) {
        int lin = i * 256 + tid, r = lin >> 6, e = lin & 63;
        BvT[e][r] = f2bf(rV[((size_t)bh * Rn + r) * En + e]);
    }
    {   // quad-per-token softmax + rope
        const int lt = tid >> 2, qd = tid & 3;
        const ushort* qrow = &QS[(size_t)(b * Ln + l0 + lt) * Dn + h * En + qd * 16];
        uint4 u0 = ((const uint4*)qrow)[0];
        uint4 u1 = ((const uint4*)qrow)[1];
        uint uw[8] = {u0.x, u0.y, u0.z, u0.w, u1.x, u1.y, u1.z, u1.w};
        float p[16];
        float s = 0.f;
        #pragma unroll
        for (int j = 0; j < 8; ++j) {
            float flo = __uint_as_float(uw[j] << 16);
            float fhi = __uint_as_float(uw[j] & 0xffff0000u);
            float e0 = __expf(flo), e1 = __expf(fhi);
            p[2 * j] = e0; p[2 * j + 1] = e1;
            s += e0 + e1;
        }
        s += __shfl_xor(s, 1);
        s += __shfl_xor(s, 2);
        float inv = 1.0f / s;
        #pragma unroll
        for (int u = 0; u < 8; ++u) {
            float A0 = p[2 * u] * inv, A1 = p[2 * u + 1] * inv;
            float2 cs = tab_pj[(l0 + lt) * 32 + qd * 8 + u];
            Ap[lt][qd * 16 + 2 * u]     = f2bf(A0 * cs.x - A1 * cs.y);
            Ap[lt][qd * 16 + 2 * u + 1] = f2bf(A0 * cs.y + A1 * cs.x);
        }
    }
    __syncthreads();
    floatx4 acc[2][2] = {};
    #pragma unroll
    for (int ks = 0; ks < 64; ks += 32) {
        bf16x8 a0 = ldsfrag(&Ap[mt + lr][ks + lq * 8]);
        bf16x8 a1 = ldsfrag(&Ap[mt + 16 + lr][ks + lq * 8]);
        bf16x8 b0 = ldsfrag(&BvT[nt + lr][ks + lq * 8]);
        bf16x8 b1 = ldsfrag(&BvT[nt + 16 + lr][ks + lq * 8]);
        acc[0][0] = MFMA(a0, b0, acc[0][0]);
        acc[0][1] = MFMA(a0, b1, acc[0][1]);
        acc[1][0] = MFMA(a1, b0, acc[1][0]);
        acc[1][1] = MFMA(a1, b1, acc[1][1]);
    }
    #pragma unroll
    for (int mi = 0; mi < 2; ++mi)
        #pragma unroll
        for (int ni = 0; ni < 2; ++ni)
            #pragma unroll
            for (int ri = 0; ri < 4; ++ri)
                Cs[mt + mi * 16 + lq * 4 + ri][nt + ni * 16 + lr] = acc[mi][ni][ri];
    __syncthreads();
    {   // vectorized epilogue: thread = (token, 16-e group)
        const int token = tid >> 2, e0 = (tid & 3) * 16;
        size_t base = (size_t)(b * Ln + l0 + token) * Dn + h * En + e0;
        uint4 sk0 = *(const uint4*)&Skip[base];
        uint4 sk1 = *(const uint4*)&Skip[base + 8];
        uint4 zz0 = *(const uint4*)&Zs[base];
        uint4 zz1 = *(const uint4*)&Zs[base + 8];
        uint sks[8] = {sk0.x, sk0.y, sk0.z, sk0.w, sk1.x, sk1.y, sk1.z, sk1.w};
        uint zzs[8] = {zz0.x, zz0.y, zz0.z, zz0.w, zz1.x, zz1.y, zz1.z, zz1.w};
        float ov[16];
        #pragma unroll
        for (int j = 0; j < 8; ++j) {
            float s0 = __uint_as_float(sks[j] << 16);
            float s1 = __uint_as_float(sks[j] & 0xffff0000u);
            float z0 = __uint_as_float(zzs[j] << 16);
            float z1 = __uint_as_float(zzs[j] & 0xffff0000u);
            ov[2 * j]     = (Cs[token][e0 + 2 * j] + s0) * z0;
            ov[2 * j + 1] = (Cs[token][e0 + 2 * j + 1] + s1) * z1;
        }
        if (f) {
            float* op = (float*)Outv + base;
            #pragma unroll
            for (int q = 0; q < 4; ++q)
                *(float4*)(op + 4 * q) = make_float4(ov[4 * q], ov[4 * q + 1],
                                                     ov[4 * q + 2], ov[4 * q + 3]);
        } else {
            ushort o16[16];
            #pragma unroll
            for (int t = 0; t < 16; ++t) o16[t] = f2bf(ov[t]);
            *(uint4*)((ushort*)Outv + base)     = *(uint4*)o16;
            *(uint4*)((ushort*)Outv + base + 8) = *(uint4*)(o16 + 8);
        }
    }
}

extern "C" void kernel_launch(void* const* d_in, const int* in_sizes, int n_in,
                              void* d_out, int out_size, void* d_ws, size_t ws_size,
                              hipStream_t stream) {
    const size_t OFF_SK    = 0;                  // 16 MiB bf16 [16384][512]
    const size_t OFF_Z     = 16777216;
    const size_t OFF_QS    = 33554432;
    const size_t OFF_E     = 50331648;           // 16 MiB bf16 E
    const size_t OFF_RV    = 67108864;           // 512 KiB f32
    const size_t OFF_L     = 67633152;           // 8 KiB f32 lsum
    const size_t OFF_TAB   = 67641344;           // 1 MiB tab_pj
    const size_t OFF_TABJP = 68689920;           // 1 MiB tab_jp
    const size_t OFF_WT    = 69738496;           // Wtcat 1536x512 bf16 = 1.5 MiB
    const size_t OFF_WKR   = 71311360;           // 512x512 bf16
    const size_t OFF_BIAS  = 71835648;           // 1536 f32
    const size_t OFF_CANON = 71841792;           // 18,944,000 B
    const size_t OFF_FLAG  = OFF_CANON + 18944000;
    const size_t NEED      = OFF_FLAG + 16;      // ~90.8 MB
    if (ws_size < NEED) return;

    char* ws = (char*)d_ws;
    ushort* skip  = (ushort*)(ws + OFF_SK);
    ushort* z     = (ushort*)(ws + OFF_Z);
    ushort* qs    = (ushort*)(ws + OFF_QS);
    ushort* E     = (ushort*)(ws + OFF_E);
    float*  rV    = (float*)(ws + OFF_RV);
    float*  lsum  = (float*)(ws + OFF_L);
    float2* tabpj = (float2*)(ws + OFF_TAB);
    float2* tabjp = (float2*)(ws + OFF_TABJP);
    ushort* Wtcat = (ushort*)(ws + OFF_WT);
    ushort* Wkr   = (ushort*)(ws + OFF_WKR);
    float*  bias  = (float*)(ws + OFF_BIAS);
    ushort* canon = (ushort*)(ws + OFF_CANON);
    int*    flag  = (int*)(ws + OFF_FLAG);

    const ushort* Xc   = canon;
    const ushort* Wqc  = canon + SEG1;
    const ushort* bqc  = canon + SEG2;
    const ushort* Wkc  = canon + SEG3;
    const ushort* Wskc = canon + SEG5;
    const ushort* bskc = canon + SEG6;
    const ushort* Wzc  = canon + SEG7;
    const ushort* bzc  = canon + SEG8;
    const ushort* RPc  = canon + SEG9;

    // host-side dtype detection: x is (4,4096,512) -> f32 = 33554432 B,
    // bf16 = 16777216 B. Fall back to the device sniffer if ambiguous.
    int mode = -1;
    if (in_sizes && n_in > 0) {
        if (in_sizes[0] == 33554432) mode = 1;
        else if (in_sizes[0] == 16777216) mode = 0;
    }
    if (mode < 0) {
        if (out_size == 33554432) mode = 1;
        else if (out_size == 16777216) mode = 0;
    }
    if (mode < 0)
        sniff_k<<<1, 256, 0, stream>>>((const uint*)d_in[0], flag);

    prep0_k<<<5268, 256, 0, stream>>>(d_in[0], d_in[1], d_in[2], d_in[3], d_in[4],
                                      d_in[5], d_in[6], d_in[7], d_in[8], d_in[9],
                                      flag, mode, canon, tabpj, tabjp, rV, lsum);
    prep1_k<<<257, 256, 0, stream>>>(Wskc, Wzc, Wqc, Wkc, RPc, bqc, bskc, bzc,
                                     Wtcat, Wkr, bias);
    big_k<<<2048, 256, 0, stream>>>(Xc, Wtcat, bias, Wkr, skip, z, qs, E, lsum);
    router_v_k<<<dim3(16, 32), 256, 0, stream>>>(E, lsum, Xc, tabjp, rV);
    final_attn_k<<<dim3(64, 8, 4), 256, 0, stream>>>(qs, rV, tabpj, skip, z, flag,
                                                     mode, d_out);
}

// Round 7
// 238.446 us; speedup vs baseline: 1.0325x; 1.0325x over previous
//
#include <hip/hip_runtime.h>

// RouterAttention on gfx950. B=4 L=S=4096 D=512 H=8 E=R=64.
// R9/R10: 1-deep pipelines NEUTRAL (78us). R12 chaining REGRESSED (93).
// R13 A-in-reg REGRESSED (110, uncoalesced 16-row A loads). Reverted.
// R14: 4-buffer ring, 3-tiles-ahead prefetch, ONE barrier/K-step, steady-state
// vmcnt(16) never 0 (AITER pattern). stage128/compute64/epilogues identical to
// the verified 78us kernel; LDS 128KB -> 1 blk/CU (occupancy axis shown cheap
// in R9). Prediction: big_k 78->55-66us if drain-stall theory holds.

#define DEV __device__ __forceinline__
#define SCHED_FENCE() __builtin_amdgcn_sched_barrier(0)

constexpr int Bn = 4, Ln = 4096, Dn = 512, Hn = 8, En = 64, Rn = 64;
constexpr int Sn = 4096;
constexpr float SCALE = 0.125f;                 // 1/sqrt(E)
constexpr float L2B_OVER_K = 13.287712379549449f / 32.0f; // log2(10000)/32

typedef __bf16 bf16x8 __attribute__((ext_vector_type(8)));
typedef float floatx4 __attribute__((ext_vector_type(4)));

DEV float bf2f(ushort u) { return __uint_as_float(((unsigned)u) << 16); }
DEV ushort f2bf(float f) {
    unsigned u = __float_as_uint(f);
    u += 0x7fffu + ((u >> 16) & 1u);            // RNE
    return (ushort)(u >> 16);
}
DEV bf16x8 ldsfrag(const ushort* p) { return *reinterpret_cast<const bf16x8*>(p); }
#define MFMA(a, b, c) __builtin_amdgcn_mfma_f32_16x16x32_bf16(a, b, c, 0, 0, 0)

DEV void gload16(const ushort* g, ushort* lds) {
    __builtin_amdgcn_global_load_lds(
        (const __attribute__((address_space(1))) unsigned int*)g,
        (__attribute__((address_space(3))) unsigned int*)lds, 16, 0, 0);
}

DEV int wave_sum_i(int v) {
    #pragma unroll
    for (int off = 1; off < 64; off <<= 1) v += __shfl_xor(v, off);
    return v;
}

// ---- dtype sniffer (fallback only): flag=1 if x looks like f32 ----
__global__ __launch_bounds__(256) void sniff_k(const uint* __restrict__ x, int* __restrict__ flag) {
    int t = threadIdx.x, cnt = 0;
    #pragma unroll
    for (int i = 0; i < 16; ++i) {
        uint u = x[t * 16 + i];
        uint e = (u >> 7) & 0xFF;
        cnt += (e >= 100 && e <= 140) ? 1 : 0;
    }
    cnt = wave_sum_i(cnt);
    __shared__ int red[4];
    int w = t >> 6, l = t & 63;
    if (l == 0) red[w] = cnt;
    __syncthreads();
    if (t == 0) flag[0] = ((red[0] + red[1] + red[2] + red[3]) < 2048) ? 1 : 0;
}

constexpr size_t SEG1 = 8388608, SEG2 = 8650752, SEG3 = 8651264, SEG4 = 8913408,
                 SEG5 = 8913920, SEG6 = 9176064, SEG7 = 9176576, SEG8 = 9438720,
                 SEG9 = 9439232, SEGT = 9472000;

// ---- prep0: canon vec8 (4625 blk) + rope tabs (512 blk) + zero (131 blk) ----
__global__ __launch_bounds__(256)
void prep0_k(const void* p0, const void* p1, const void* p2, const void* p3,
             const void* p4, const void* p5, const void* p6, const void* p7,
             const void* p8, const void* p9, const int* __restrict__ flag,
             int fhost,
             ushort* __restrict__ dst, float2* __restrict__ tab_pj,
             float2* __restrict__ tab_jp, float* __restrict__ rV,
             float* __restrict__ lsum) {
    const int bid = blockIdx.x, tid = threadIdx.x;
    if (bid < 4625) {                           // canon: 8 elems/thread
        const int f = (fhost >= 0) ? fhost : *flag;
        size_t i = ((size_t)bid * 256 + tid) * 8;   // all SEG bounds %8==0
        const void* sp; size_t off;
        if      (i < SEG1) { sp = p0; off = i; }
        else if (i < SEG2) { sp = p1; off = i - SEG1; }
        else if (i < SEG3) { sp = p2; off = i - SEG2; }
        else if (i < SEG4) { sp = p3; off = i - SEG3; }
        else if (i < SEG5) { sp = p4; off = i - SEG4; }
        else if (i < SEG6) { sp = p5; off = i - SEG5; }
        else if (i < SEG7) { sp = p6; off = i - SEG6; }
        else if (i < SEG8) { sp = p7; off = i - SEG7; }
        else if (i < SEG9) { sp = p8; off = i - SEG8; }
        else               { sp = p9; off = i - SEG9; }
        ushort o8[8];
        if (f) {
            float4 a = *((const float4*)((const float*)sp + off));
            float4 b = *((const float4*)((const float*)sp + off) + 1);
            o8[0] = f2bf(a.x); o8[1] = f2bf(a.y); o8[2] = f2bf(a.z); o8[3] = f2bf(a.w);
            o8[4] = f2bf(b.x); o8[5] = f2bf(b.y); o8[6] = f2bf(b.z); o8[7] = f2bf(b.w);
        } else {
            *(uint4*)o8 = *(const uint4*)((const ushort*)sp + off);
        }
        *(uint4*)&dst[i] = *(uint4*)o8;
    } else if (bid < 5137) {                    // rope tables (both layouts)
        int idx = (bid - 4625) * 256 + tid;     // 131072 entries
        int p = idx >> 5, j = idx & 31;
        float theta = exp2f(-(float)j * L2B_OVER_K);
        float ang = (float)(Sn - 1 - p) * theta;
        float s, c;
        sincosf(ang, &s, &c);
        tab_pj[idx] = make_float2(c, s);
        tab_jp[j * Sn + p] = make_float2(c, s);
    } else {                                    // zero rV + lsum
        int base = (bid - 5137) * 1024 + tid;
        #pragma unroll
        for (int r = 0; r < 4; ++r) {
            int f32i = base + r * 256;
            if (f32i < 131072) rV[f32i] = 0.f;
            else if (f32i < 133120) lsum[f32i - 131072] = 0.f;
        }
    }
}

// ---- prep1: 2 transposes (128 blk) + prep_wr (128 blk) + prep_bias (1 blk) ----
__global__ __launch_bounds__(256)
void prep1_k(const ushort* __restrict__ Wskc, const ushort* __restrict__ Wzc,
             const ushort* __restrict__ Wqc, const ushort* __restrict__ Wkc,
             const ushort* __restrict__ RPc, const ushort* __restrict__ bqc,
             const ushort* __restrict__ bskc, const ushort* __restrict__ bzc,
             ushort* __restrict__ Wtcat, ushort* __restrict__ Wkr,
             float* __restrict__ biascat) {
    __shared__ ushort t64[64][65];
    __shared__ ushort As1[64][72];
    __shared__ ushort Bs1[64][72];
    const int bid = blockIdx.x, tid = threadIdx.x;
    if (bid < 128) {                            // transpose: Wt[dout][din]
        const ushort* W = (bid < 64) ? Wskc : Wzc;
        ushort* Wt = Wtcat + (bid < 64 ? 0 : 262144);
        int bb = bid & 63;
        int bx = (bb & 7) * 64, by = (bb >> 3) * 64;
        int c = tid & 63, r0 = (tid >> 6) * 16;
        #pragma unroll
        for (int i = 0; i < 16; ++i) t64[r0 + i][c] = W[(size_t)(by + r0 + i) * Dn + bx + c];
        __syncthreads();
        #pragma unroll
        for (int i = 0; i < 16; ++i) Wt[(size_t)(bx + r0 + i) * Dn + by + c] = t64[c][r0 + i];
    } else if (bid < 256) {                     // prep_wr
        int idx = bid - 128;
        int zsel = idx >> 6, rem = idx & 63;
        int d0 = (rem & 7) * 64, h = rem >> 3;
        const ushort* W = zsel ? Wkc : Wqc;
        ushort* Out = zsel ? Wkr : (Wtcat + 524288);
        #pragma unroll
        for (int j = 0; j < 2; ++j) {
            int lin = j * 256 + tid, row = lin >> 3, c = (lin & 7) * 8;
            *(uint4*)&As1[row][c] = *(const uint4*)&RPc[(size_t)row * Dn + h * En + c];
            *(uint4*)&Bs1[row][c] = *(const uint4*)&W[(size_t)(d0 + row) * Dn + h * En + c];
        }
        __syncthreads();
        const int w = tid >> 6, l = tid & 63;
        const int mt = (w >> 1) * 32, nt = (w & 1) * 32, lr = l & 15, lq = l >> 4;
        floatx4 acc[2][2] = {};
        #pragma unroll
        for (int ks = 0; ks < 64; ks += 32) {
            bf16x8 a0 = ldsfrag(&As1[mt + lr][ks + lq * 8]);
            bf16x8 a1 = ldsfrag(&As1[mt + 16 + lr][ks + lq * 8]);
            bf16x8 b0 = ldsfrag(&Bs1[nt + lr][ks + lq * 8]);
            bf16x8 b1 = ldsfrag(&Bs1[nt + 16 + lr][ks + lq * 8]);
            acc[0][0] = MFMA(a0, b0, acc[0][0]);
            acc[0][1] = MFMA(a0, b1, acc[0][1]);
            acc[1][0] = MFMA(a1, b0, acc[1][0]);
            acc[1][1] = MFMA(a1, b1, acc[1][1]);
        }
        #pragma unroll
        for (int mi = 0; mi < 2; ++mi)
            #pragma unroll
            for (int ni = 0; ni < 2; ++ni)
                #pragma unroll
                for (int ri = 0; ri < 4; ++ri) {
                    int ro = mt + mi * 16 + lq * 4 + ri;
                    int d = d0 + nt + ni * 16 + lr;
                    Out[(size_t)(h * En + ro) * Dn + d] = f2bf(acc[mi][ni][ri] * SCALE);
                }
    } else {                                    // prep_bias
        #pragma unroll
        for (int it = 0; it < 2; ++it) {
            int i = it * 256 + tid;
            biascat[i]       = bf2f(bskc[i]);
            biascat[512 + i] = bf2f(bzc[i]);
            int h = i >> 6, ro = i & 63;
            float s = 0.f;
            for (int e = 0; e < 64; ++e)
                s += bf2f(bqc[h * En + e]) * bf2f(RPc[(size_t)ro * Dn + h * En + e]);
            biascat[1024 + i] = s * SCALE;
        }
    }
}

// ---- verified 128x128 tile pieces (identical to the 78us kernel) ----
DEV void stage128(const ushort* __restrict__ Ag, const ushort* __restrict__ Bg,
                  int m0, int n0, int kc, ushort* As, ushort* Bs, int w, int l) {
    #pragma unroll
    for (int j = 0; j < 4; ++j) {
        int slot = (w * 4 + j) * 64 + l;
        int row = slot >> 3;
        int c = ((slot & 7) - row) & 7;
        gload16(&Ag[(size_t)(m0 + row) * Dn + kc + c * 8], &As[(w * 4 + j) * 512]);
        gload16(&Bg[(size_t)(n0 + row) * Dn + kc + c * 8], &Bs[(w * 4 + j) * 512]);
    }
}

DEV void compute64(const ushort* As, const ushort* Bs, int mt, int nt,
                   int lr, int lq, floatx4 (&acc)[4][4]) {
    #pragma unroll
    for (int ks = 0; ks < 64; ks += 32) {
        bf16x8 a[4], bb[4];
        const int cc = (ks >> 3) + lq;
        #pragma unroll
        for (int i = 0; i < 4; ++i) {
            int row = mt + 16 * i + lr;
            a[i] = ldsfrag(&As[(row * 8 + ((cc + row) & 7)) * 8]);
        }
        #pragma unroll
        for (int i = 0; i < 4; ++i) {
            int row = nt + 16 * i + lr;
            bb[i] = ldsfrag(&Bs[(row * 8 + ((cc + row) & 7)) * 8]);
        }
        #pragma unroll
        for (int mi = 0; mi < 4; ++mi)
            #pragma unroll
            for (int ni = 0; ni < 4; ++ni)
                acc[mi][ni] = MFMA(a[mi], bb[ni], acc[mi][ni]);
    }
}

// 4-buffer ring, 3 K-tiles prefetched ahead, ONE barrier per K-step.
// Iteration t: stage(t+3) -> buf[(t+3)&3]   (overwrite-safe: buf freed at the
//   barrier ending tile t-1); compute buf[t&3]; lgkmcnt(0) (my LDS reads
//   retired); vmcnt(16) = wait tile t+1 only (its 8 loads are the oldest;
//   16 = tiles t+2,t+3 still in flight); barrier (publish t+1 + free t).
// Steady state never waits vmcnt(0).
DEV void kloop128(const ushort* __restrict__ Ag, const ushort* __restrict__ Bg,
                  int m0, int n0, ushort* As, ushort* Bs, int tid,
                  floatx4 (&acc)[4][4]) {
    const int w = tid >> 6, l = tid & 63;
    const int mt = (w >> 1) * 64, nt = (w & 1) * 64;
    const int lr = l & 15, lq = l >> 4;
    stage128(Ag, Bg, m0, n0, 0,   As,         Bs,         w, l);
    stage128(Ag, Bg, m0, n0, 64,  As + 8192,  Bs + 8192,  w, l);
    stage128(Ag, Bg, m0, n0, 128, As + 16384, Bs + 16384, w, l);
    asm volatile("s_waitcnt vmcnt(16)" ::: "memory");  // tile 0 landed
    SCHED_FENCE();
    __builtin_amdgcn_s_barrier();
    SCHED_FENCE();
    #pragma unroll
    for (int t = 0; t < 8; ++t) {
        if (t < 5)
            stage128(Ag, Bg, m0, n0, (t + 3) * 64,
                     As + ((t + 3) & 3) * 8192, Bs + ((t + 3) & 3) * 8192, w, l);
        compute64(As + (t & 3) * 8192, Bs + (t & 3) * 8192, mt, nt, lr, lq, acc);
        if (t < 7) {
            asm volatile("s_waitcnt lgkmcnt(0)" ::: "memory");
            SCHED_FENCE();
            if (t < 5)       { asm volatile("s_waitcnt vmcnt(16)" ::: "memory"); }
            else if (t == 5) { asm volatile("s_waitcnt vmcnt(8)"  ::: "memory"); }
            else             { asm volatile("s_waitcnt vmcnt(0)"  ::: "memory"); }
            SCHED_FENCE();
            __builtin_amdgcn_s_barrier();
            SCHED_FENCE();
        }
    }
}

// ---- big_k: proj (1536) + rscore (512), XCD-chunk swizzled (2048 = 8*256) ----
__global__ __launch_bounds__(256)
void big_k(const ushort* __restrict__ X, const ushort* __restrict__ Wtcat,
           const float* __restrict__ biascat, const ushort* __restrict__ Wkr,
           ushort* __restrict__ skip, ushort* __restrict__ z,
           ushort* __restrict__ qs, ushort* __restrict__ E,
           float* __restrict__ lsum) {
    __shared__ __align__(16) ushort As[32768];  // 4 x 16KB ring
    __shared__ __align__(16) ushort Bs[32768];  // 4 x 16KB ring
    const int bid = blockIdx.x, tid = threadIdx.x;
    const int w = tid >> 6, l = tid & 63;
    const int mt = (w >> 1) * 64, nt = (w & 1) * 64;
    const int lr = l & 15, lq = l >> 4;
    const int swz = (bid & 7) * 256 + (bid >> 3);   // bijective XCD swizzle
    floatx4 acc[4][4] = {};
    if (swz < 1536) {                           // ---- projection GEMM ----
        const int n0 = (swz % 12) * 128;
        const int m0 = (swz / 12) * 128;
        kloop128(X, Wtcat, m0, n0, As, Bs, tid, acc);
        const int sec = n0 >> 9;                // 0=skip 1=z 2=qs
        ushort* dst = sec == 0 ? skip : (sec == 1 ? z : qs);
        #pragma unroll
        for (int ni = 0; ni < 4; ++ni) {
            int ng = n0 + nt + ni * 16 + lr;
            float bbv = biascat[ng];
            int nc = ng & 511;
            #pragma unroll
            for (int mi = 0; mi < 4; ++mi)
                #pragma unroll
                for (int ri = 0; ri < 4; ++ri) {
                    int row = m0 + mt + mi * 16 + lq * 4 + ri;
                    float v = acc[mi][ni][ri] + bbv;
                    if (sec == 1) v = v / (1.0f + __expf(-v));
                    dst[(size_t)row * Dn + nc] = f2bf(v);
                }
        }
    } else {                                    // ---- router scores GEMM ----
        int idx = swz - 1536;                   // 0..511
        const int n0 = (idx & 127) * 128;       // x row = b*4096+s
        const int m0 = (idx >> 7) * 128;        // Wkr row = h*64+r
        kloop128(Wkr, X, m0, n0, As, Bs, tid, acc);
        const int b = n0 >> 12;
        const int sbase = (n0 & 4095) + nt;
        #pragma unroll
        for (int mi = 0; mi < 4; ++mi)
            #pragma unroll
            for (int ri = 0; ri < 4; ++ri) {
                size_t row = (size_t)(b * 512 + m0 + mt + mi * 16 + lq * 4 + ri);
                float rs = 0.f;
                #pragma unroll
                for (int ni = 0; ni < 4; ++ni) {
                    int s = sbase + ni * 16 + lr;
                    float e = __expf(acc[mi][ni][ri]);
                    E[row * Sn + s] = f2bf(e);
                    rs += e;
                }
                rs += __shfl_xor(rs, 1); rs += __shfl_xor(rs, 2);
                rs += __shfl_xor(rs, 4); rs += __shfl_xor(rs, 8);
                if (lr == 0) atomicAdd(&lsum[row], rs);
            }
    }
}

// ---- rV[bh][r][e] += sum_s rope(E/l)[r][s] * v[s][e]; 2 chunks/block ----
__global__ __launch_bounds__(256)
void router_v_k(const ushort* __restrict__ E, const float* __restrict__ lsum,
                const ushort* __restrict__ X, const float2* __restrict__ tab_jp,
                float* __restrict__ rV) {
    __shared__ ushort As[64][136];   // rope(E/l)[r][s0..127]
    __shared__ ushort Bs[64][136];   // v^T[e][s]
    __shared__ float invl[64];
    const int tid = threadIdx.x;
    const int bh = blockIdx.y, b = bh >> 3, h = bh & 7;
    const int s0 = blockIdx.x * 256;
    const int w = tid >> 6, l = tid & 63;
    const int mt = (w >> 1) * 32, nt = (w & 1) * 32, lr = l & 15, lq = l >> 4;
    if (tid < 64) invl[tid] = 1.0f / lsum[(size_t)bh * Rn + tid];
    __syncthreads();
    floatx4 acc[2][2] = {};
    for (int c = 0; c < 2; ++c) {
        const int sb = s0 + c * 128;
        if (c) __syncthreads();                 // all waves done with chunk c-1
        #pragma unroll
        for (int it = 0; it < 4; ++it) {        // rope staging: 4 s per thread
            int lin = it * 256 + tid;
            int j = lin >> 5, sq = (lin & 31) * 4, sg = sb + sq;
            const ushort* ep = &E[((size_t)bh * Rn + 2 * j) * Sn + sg];
            uint2 ue = *(const uint2*)ep;
            uint2 uo = *(const uint2*)(ep + Sn);
            float4 t01 = *(const float4*)&tab_jp[(size_t)j * Sn + sg];
            float4 t23 = *(const float4*)&tab_jp[(size_t)j * Sn + sg + 2];
            float il_e = invl[2 * j], il_o = invl[2 * j + 1];
            float pe0 = bf2f((ushort)(ue.x & 0xffff)) * il_e;
            float pe1 = bf2f((ushort)(ue.x >> 16)) * il_e;
            float pe2 = bf2f((ushort)(ue.y & 0xffff)) * il_e;
            float pe3 = bf2f((ushort)(ue.y >> 16)) * il_e;
            float po0 = bf2f((ushort)(uo.x & 0xffff)) * il_o;
            float po1 = bf2f((ushort)(uo.x >> 16)) * il_o;
            float po2 = bf2f((ushort)(uo.y & 0xffff)) * il_o;
            float po3 = bf2f((ushort)(uo.y >> 16)) * il_o;
            ushort re[4], ro[4];
            re[0] = f2bf(pe0 * t01.x - po0 * t01.y);
            ro[0] = f2bf(pe0 * t01.y + po0 * t01.x);
            re[1] = f2bf(pe1 * t01.z - po1 * t01.w);
            ro[1] = f2bf(pe1 * t01.w + po1 * t01.z);
            re[2] = f2bf(pe2 * t23.x - po2 * t23.y);
            ro[2] = f2bf(pe2 * t23.y + po2 * t23.x);
            re[3] = f2bf(pe3 * t23.z - po3 * t23.w);
            ro[3] = f2bf(pe3 * t23.w + po3 * t23.z);
            *(uint2*)&As[2 * j][sq]     = *(uint2*)re;
            *(uint2*)&As[2 * j + 1][sq] = *(uint2*)ro;
        }
        #pragma unroll
        for (int it = 0; it < 4; ++it) {        // v^T staging, uint4 loads
            int lin = it * 256 + tid;
            int s = lin >> 3, eg = (lin & 7) * 8;
            ushort u8[8];
            *(uint4*)u8 = *(const uint4*)&X[(size_t)(b * Ln + sb + s) * Dn + h * En + eg];
            #pragma unroll
            for (int t = 0; t < 8; ++t) Bs[eg + t][s] = u8[t];
        }
        __syncthreads();
        #pragma unroll
        for (int ks = 0; ks < 128; ks += 32) {
            bf16x8 a0 = ldsfrag(&As[mt + lr][ks + lq * 8]);
            bf16x8 a1 = ldsfrag(&As[mt + 16 + lr][ks + lq * 8]);
            bf16x8 b0 = ldsfrag(&Bs[nt + lr][ks + lq * 8]);
            bf16x8 b1 = ldsfrag(&Bs[nt + 16 + lr][ks + lq * 8]);
            acc[0][0] = MFMA(a0, b0, acc[0][0]);
            acc[0][1] = MFMA(a0, b1, acc[0][1]);
            acc[1][0] = MFMA(a1, b0, acc[1][0]);
            acc[1][1] = MFMA(a1, b1, acc[1][1]);
        }
    }
    #pragma unroll
    for (int mi = 0; mi < 2; ++mi)
        #pragma unroll
        for (int ni = 0; ni < 2; ++ni)
            #pragma unroll
            for (int ri = 0; ri < 4; ++ri) {
                int r = mt + mi * 16 + lq * 4 + ri;
                int e = nt + ni * 16 + lr;
                atomicAdd(&rV[((size_t)bh * Rn + r) * En + e], acc[mi][ni][ri]);
            }
}

// ---- fused query path: qs -> in-thread softmax -> rope -> @rV -> (+skip)*z ----
__global__ __launch_bounds__(256)
void final_attn_k(const ushort* __restrict__ QS, const float* __restrict__ rV,
                  const float2* __restrict__ tab_pj, const ushort* __restrict__ Skip,
                  const ushort* __restrict__ Zs, const int* __restrict__ flagp,
                  int fhost, void* __restrict__ Outv) {
    __shared__ ushort Ap[64][72];
    __shared__ ushort BvT[64][72];
    __shared__ float Cs[64][68];
    const int f = (fhost >= 0) ? fhost : *flagp;
    const int tid = threadIdx.x;
    const int h = blockIdx.y, b = blockIdx.z, bh = b * Hn + h;
    const int l0 = blockIdx.x * 64;
    const int w = tid >> 6, l = tid & 63;
    const int mt = (w >> 1) * 32, nt = (w & 1) * 32, lr = l & 15, lq = l >> 4;
    #pragma unroll
    for (int i = 0; i < 16; ++i) {
        int lin = i * 256 + tid, r = lin >> 6, e = lin & 63;
        BvT[e][r] = f2bf(rV[((size_t)bh * Rn + r) * En + e]);
    }
    {   // quad-per-token softmax + rope
        const int lt = tid >> 2, qd = tid & 3;
        const ushort* qrow = &QS[(size_t)(b * Ln + l0 + lt) * Dn + h * En + qd * 16];
        uint4 u0 = ((const uint4*)qrow)[0];
        uint4 u1 = ((const uint4*)qrow)[1];
        uint uw[8] = {u0.x, u0.y, u0.z, u0.w, u1.x, u1.y, u1.z, u1.w};
        float p[16];
        float s = 0.f;
        #pragma unroll
        for (int j = 0; j < 8; ++j) {
            float flo = __uint_as_float(uw[j] << 16);
            float fhi = __uint_as_float(uw[j] & 0xffff0000u);
            float e0 = __expf(flo), e1 = __expf(fhi);
            p[2 * j] = e0; p[2 * j + 1] = e1;
            s += e0 + e1;
        }
        s += __shfl_xor(s, 1);
        s += __shfl_xor(s, 2);
        float inv = 1.0f / s;
        #pragma unroll
        for (int u = 0; u < 8; ++u) {
            float A0 = p[2 * u] * inv, A1 = p[2 * u + 1] * inv;
            float2 cs = tab_pj[(l0 + lt) * 32 + qd * 8 + u];
            Ap[lt][qd * 16 + 2 * u]     = f2bf(A0 * cs.x - A1 * cs.y);
            Ap[lt][qd * 16 + 2 * u + 1] = f2bf(A0 * cs.y + A1 * cs.x);
        }
    }
    __syncthreads();
    floatx4 acc[2][2] = {};
    #pragma unroll
    for (int ks = 0; ks < 64; ks += 32) {
        bf16x8 a0 = ldsfrag(&Ap[mt + lr][ks + lq * 8]);
        bf16x8 a1 = ldsfrag(&Ap[mt + 16 + lr][ks + lq * 8]);
        bf16x8 b0 = ldsfrag(&BvT[nt + lr][ks + lq * 8]);
        bf16x8 b1 = ldsfrag(&BvT[nt + 16 + lr][ks + lq * 8]);
        acc[0][0] = MFMA(a0, b0, acc[0][0]);
        acc[0][1] = MFMA(a0, b1, acc[0][1]);
        acc[1][0] = MFMA(a1, b0, acc[1][0]);
        acc[1][1] = MFMA(a1, b1, acc[1][1]);
    }
    #pragma unroll
    for (int mi = 0; mi < 2; ++mi)
        #pragma unroll
        for (int ni = 0; ni < 2; ++ni)
            #pragma unroll
            for (int ri = 0; ri < 4; ++ri)
                Cs[mt + mi * 16 + lq * 4 + ri][nt + ni * 16 + lr] = acc[mi][ni][ri];
    __syncthreads();
    {   // vectorized epilogue: thread = (token, 16-e group)
        const int token = tid >> 2, e0 = (tid & 3) * 16;
        size_t base = (size_t)(b * Ln + l0 + token) * Dn + h * En + e0;
        uint4 sk0 = *(const uint4*)&Skip[base];
        uint4 sk1 = *(const uint4*)&Skip[base + 8];
        uint4 zz0 = *(const uint4*)&Zs[base];
        uint4 zz1 = *(const uint4*)&Zs[base + 8];
        uint sks[8] = {sk0.x, sk0.y, sk0.z, sk0.w, sk1.x, sk1.y, sk1.z, sk1.w};
        uint zzs[8] = {zz0.x, zz0.y, zz0.z, zz0.w, zz1.x, zz1.y, zz1.z, zz1.w};
        float ov[16];
        #pragma unroll
        for (int j = 0; j < 8; ++j) {
            float s0 = __uint_as_float(sks[j] << 16);
            float s1 = __uint_as_float(sks[j] & 0xffff0000u);
            float z0 = __uint_as_float(zzs[j] << 16);
            float z1 = __uint_as_float(zzs[j] & 0xffff0000u);
            ov[2 * j]     = (Cs[token][e0 + 2 * j] + s0) * z0;
            ov[2 * j + 1] = (Cs[token][e0 + 2 * j + 1] + s1) * z1;
        }
        if (f) {
            float* op = (float*)Outv + base;
            #pragma unroll
            for (int q = 0; q < 4; ++q)
                *(float4*)(op + 4 * q) = make_float4(ov[4 * q], ov[4 * q + 1],
                                                     ov[4 * q + 2], ov[4 * q + 3]);
        } else {
            ushort o16[16];
            #pragma unroll
            for (int t = 0; t < 16; ++t) o16[t] = f2bf(ov[t]);
            *(uint4*)((ushort*)Outv + base)     = *(uint4*)o16;
            *(uint4*)((ushort*)Outv + base + 8) = *(uint4*)(o16 + 8);
        }
    }
}

extern "C" void kernel_launch(void* const* d_in, const int* in_sizes, int n_in,
                              void* d_out, int out_size, void* d_ws, size_t ws_size,
                              hipStream_t stream) {
    const size_t OFF_SK    = 0;                  // 16 MiB bf16 [16384][512]
    const size_t OFF_Z     = 16777216;
    const size_t OFF_QS    = 33554432;
    const size_t OFF_E     = 50331648;           // 16 MiB bf16 E
    const size_t OFF_RV    = 67108864;           // 512 KiB f32
    const size_t OFF_L     = 67633152;           // 8 KiB f32 lsum
    const size_t OFF_TAB   = 67641344;           // 1 MiB tab_pj
    const size_t OFF_TABJP = 68689920;           // 1 MiB tab_jp
    const size_t OFF_WT    = 69738496;           // Wtcat 1536x512 bf16 = 1.5 MiB
    const size_t OFF_WKR   = 71311360;           // 512x512 bf16
    const size_t OFF_BIAS  = 71835648;           // 1536 f32
    const size_t OFF_CANON = 71841792;           // 18,944,000 B
    const size_t OFF_FLAG  = OFF_CANON + 18944000;
    const size_t NEED      = OFF_FLAG + 16;      // ~90.8 MB
    if (ws_size < NEED) return;

    char* ws = (char*)d_ws;
    ushort* skip  = (ushort*)(ws + OFF_SK);
    ushort* z     = (ushort*)(ws + OFF_Z);
    ushort* qs    = (ushort*)(ws + OFF_QS);
    ushort* E     = (ushort*)(ws + OFF_E);
    float*  rV    = (float*)(ws + OFF_RV);
    float*  lsum  = (float*)(ws + OFF_L);
    float2* tabpj = (float2*)(ws + OFF_TAB);
    float2* tabjp = (float2*)(ws + OFF_TABJP);
    ushort* Wtcat = (ushort*)(ws + OFF_WT);
    ushort* Wkr   = (ushort*)(ws + OFF_WKR);
    float*  bias  = (float*)(ws + OFF_BIAS);
    ushort* canon = (ushort*)(ws + OFF_CANON);
    int*    flag  = (int*)(ws + OFF_FLAG);

    const ushort* Xc   = canon;
    const ushort* Wqc  = canon + SEG1;
    const ushort* bqc  = canon + SEG2;
    const ushort* Wkc  = canon + SEG3;
    const ushort* Wskc = canon + SEG5;
    const ushort* bskc = canon + SEG6;
    const ushort* Wzc  = canon + SEG7;
    const ushort* bzc  = canon + SEG8;
    const ushort* RPc  = canon + SEG9;

    // host-side dtype detection: x is (4,4096,512) -> f32 = 33554432 B,
    // bf16 = 16777216 B. Fall back to the device sniffer if ambiguous.
    int mode = -1;
    if (in_sizes && n_in > 0) {
        if (in_sizes[0] == 33554432) mode = 1;
        else if (in_sizes[0] == 16777216) mode = 0;
    }
    if (mode < 0) {
        if (out_size == 33554432) mode = 1;
        else if (out_size == 16777216) mode = 0;
    }
    if (mode < 0)
        sniff_k<<<1, 256, 0, stream>>>((const uint*)d_in[0], flag);

    prep0_k<<<5268, 256, 0, stream>>>(d_in[0], d_in[1], d_in[2], d_in[3], d_in[4],
                                      d_in[5], d_in[6], d_in[7], d_in[8], d_in[9],
                                      flag, mode, canon, tabpj, tabjp, rV, lsum);
    prep1_k<<<257, 256, 0, stream>>>(Wskc, Wzc, Wqc, Wkc, RPc, bqc, bskc, bzc,
                                     Wtcat, Wkr, bias);
    big_k<<<2048, 256, 0, stream>>>(Xc, Wtcat, bias, Wkr, skip, z, qs, E, lsum);
    router_v_k<<<dim3(16, 32), 256, 0, stream>>>(E, lsum, Xc, tabjp, rV);
    final_attn_k<<<dim3(64, 8, 4), 256, 0, stream>>>(qs, rV, tabpj, skip, z, flag,
                                                     mode, d_out);
}

// Round 8
// 206.177 us; speedup vs baseline: 1.1941x; 1.1565x over previous
//
#include <hip/hip_runtime.h>

// RouterAttention on gfx950. B=4 L=S=4096 D=512 H=8 E=R=64.
// Schedule-space ledger for big_k @128^2 tile (all refcheck'd):
//   R8 serial 2-barrier 32KB/5blk-CU: 77.2us  <-- BEST, restored here
//   R9 dbuf / R10 counted-vmcnt(1-deep): 78 (neutral; barrier drain dominates)
//   R12 chaining: 93.7 / R13 A-in-reg: 110 / R14 4-ring: 112 (all regressed:
//   each traded TLP for ILP and lost). 128^2 structure declared pinned.
// R15: revert big_k to R8-exact; keep host-side dtype (no sniff launch) and
// R11 router_v (K=256/block, vectorized staging). Next lever if this
// confirms ~206: 256^2 8-phase port of the projection GEMM.

#define DEV __device__ __forceinline__

constexpr int Bn = 4, Ln = 4096, Dn = 512, Hn = 8, En = 64, Rn = 64;
constexpr int Sn = 4096;
constexpr float SCALE = 0.125f;                 // 1/sqrt(E)
constexpr float L2B_OVER_K = 13.287712379549449f / 32.0f; // log2(10000)/32

typedef __bf16 bf16x8 __attribute__((ext_vector_type(8)));
typedef float floatx4 __attribute__((ext_vector_type(4)));

DEV float bf2f(ushort u) { return __uint_as_float(((unsigned)u) << 16); }
DEV ushort f2bf(float f) {
    unsigned u = __float_as_uint(f);
    u += 0x7fffu + ((u >> 16) & 1u);            // RNE
    return (ushort)(u >> 16);
}
DEV bf16x8 ldsfrag(const ushort* p) { return *reinterpret_cast<const bf16x8*>(p); }
#define MFMA(a, b, c) __builtin_amdgcn_mfma_f32_16x16x32_bf16(a, b, c, 0, 0, 0)

DEV void gload16(const ushort* g, ushort* lds) {
    __builtin_amdgcn_global_load_lds(
        (const __attribute__((address_space(1))) unsigned int*)g,
        (__attribute__((address_space(3))) unsigned int*)lds, 16, 0, 0);
}

DEV int wave_sum_i(int v) {
    #pragma unroll
    for (int off = 1; off < 64; off <<= 1) v += __shfl_xor(v, off);
    return v;
}

// ---- dtype sniffer (fallback only): flag=1 if x looks like f32 ----
__global__ __launch_bounds__(256) void sniff_k(const uint* __restrict__ x, int* __restrict__ flag) {
    int t = threadIdx.x, cnt = 0;
    #pragma unroll
    for (int i = 0; i < 16; ++i) {
        uint u = x[t * 16 + i];
        uint e = (u >> 7) & 0xFF;
        cnt += (e >= 100 && e <= 140) ? 1 : 0;
    }
    cnt = wave_sum_i(cnt);
    __shared__ int red[4];
    int w = t >> 6, l = t & 63;
    if (l == 0) red[w] = cnt;
    __syncthreads();
    if (t == 0) flag[0] = ((red[0] + red[1] + red[2] + red[3]) < 2048) ? 1 : 0;
}

constexpr size_t SEG1 = 8388608, SEG2 = 8650752, SEG3 = 8651264, SEG4 = 8913408,
                 SEG5 = 8913920, SEG6 = 9176064, SEG7 = 9176576, SEG8 = 9438720,
                 SEG9 = 9439232, SEGT = 9472000;

// ---- prep0: canon vec8 (4625 blk) + rope tabs (512 blk) + zero (131 blk) ----
__global__ __launch_bounds__(256)
void prep0_k(const void* p0, const void* p1, const void* p2, const void* p3,
             const void* p4, const void* p5, const void* p6, const void* p7,
             const void* p8, const void* p9, const int* __restrict__ flag,
             int fhost,
             ushort* __restrict__ dst, float2* __restrict__ tab_pj,
             float2* __restrict__ tab_jp, float* __restrict__ rV,
             float* __restrict__ lsum) {
    const int bid = blockIdx.x, tid = threadIdx.x;
    if (bid < 4625) {                           // canon: 8 elems/thread
        const int f = (fhost >= 0) ? fhost : *flag;
        size_t i = ((size_t)bid * 256 + tid) * 8;   // all SEG bounds %8==0
        const void* sp; size_t off;
        if      (i < SEG1) { sp = p0; off = i; }
        else if (i < SEG2) { sp = p1; off = i - SEG1; }
        else if (i < SEG3) { sp = p2; off = i - SEG2; }
        else if (i < SEG4) { sp = p3; off = i - SEG3; }
        else if (i < SEG5) { sp = p4; off = i - SEG4; }
        else if (i < SEG6) { sp = p5; off = i - SEG5; }
        else if (i < SEG7) { sp = p6; off = i - SEG6; }
        else if (i < SEG8) { sp = p7; off = i - SEG7; }
        else if (i < SEG9) { sp = p8; off = i - SEG8; }
        else               { sp = p9; off = i - SEG9; }
        ushort o8[8];
        if (f) {
            float4 a = *((const float4*)((const float*)sp + off));
            float4 b = *((const float4*)((const float*)sp + off) + 1);
            o8[0] = f2bf(a.x); o8[1] = f2bf(a.y); o8[2] = f2bf(a.z); o8[3] = f2bf(a.w);
            o8[4] = f2bf(b.x); o8[5] = f2bf(b.y); o8[6] = f2bf(b.z); o8[7] = f2bf(b.w);
        } else {
            *(uint4*)o8 = *(const uint4*)((const ushort*)sp + off);
        }
        *(uint4*)&dst[i] = *(uint4*)o8;
    } else if (bid < 5137) {                    // rope tables (both layouts)
        int idx = (bid - 4625) * 256 + tid;     // 131072 entries
        int p = idx >> 5, j = idx & 31;
        float theta = exp2f(-(float)j * L2B_OVER_K);
        float ang = (float)(Sn - 1 - p) * theta;
        float s, c;
        sincosf(ang, &s, &c);
        tab_pj[idx] = make_float2(c, s);
        tab_jp[j * Sn + p] = make_float2(c, s);
    } else {                                    // zero rV + lsum
        int base = (bid - 5137) * 1024 + tid;
        #pragma unroll
        for (int r = 0; r < 4; ++r) {
            int f32i = base + r * 256;
            if (f32i < 131072) rV[f32i] = 0.f;
            else if (f32i < 133120) lsum[f32i - 131072] = 0.f;
        }
    }
}

// ---- prep1: 2 transposes (128 blk) + prep_wr (128 blk) + prep_bias (1 blk) ----
__global__ __launch_bounds__(256)
void prep1_k(const ushort* __restrict__ Wskc, const ushort* __restrict__ Wzc,
             const ushort* __restrict__ Wqc, const ushort* __restrict__ Wkc,
             const ushort* __restrict__ RPc, const ushort* __restrict__ bqc,
             const ushort* __restrict__ bskc, const ushort* __restrict__ bzc,
             ushort* __restrict__ Wtcat, ushort* __restrict__ Wkr,
             float* __restrict__ biascat) {
    __shared__ ushort t64[64][65];
    __shared__ ushort As1[64][72];
    __shared__ ushort Bs1[64][72];
    const int bid = blockIdx.x, tid = threadIdx.x;
    if (bid < 128) {                            // transpose: Wt[dout][din]
        const ushort* W = (bid < 64) ? Wskc : Wzc;
        ushort* Wt = Wtcat + (bid < 64 ? 0 : 262144);
        int bb = bid & 63;
        int bx = (bb & 7) * 64, by = (bb >> 3) * 64;
        int c = tid & 63, r0 = (tid >> 6) * 16;
        #pragma unroll
        for (int i = 0; i < 16; ++i) t64[r0 + i][c] = W[(size_t)(by + r0 + i) * Dn + bx + c];
        __syncthreads();
        #pragma unroll
        for (int i = 0; i < 16; ++i) Wt[(size_t)(bx + r0 + i) * Dn + by + c] = t64[c][r0 + i];
    } else if (bid < 256) {                     // prep_wr
        int idx = bid - 128;
        int zsel = idx >> 6, rem = idx & 63;
        int d0 = (rem & 7) * 64, h = rem >> 3;
        const ushort* W = zsel ? Wkc : Wqc;
        ushort* Out = zsel ? Wkr : (Wtcat + 524288);
        #pragma unroll
        for (int j = 0; j < 2; ++j) {
            int lin = j * 256 + tid, row = lin >> 3, c = (lin & 7) * 8;
            *(uint4*)&As1[row][c] = *(const uint4*)&RPc[(size_t)row * Dn + h * En + c];
            *(uint4*)&Bs1[row][c] = *(const uint4*)&W[(size_t)(d0 + row) * Dn + h * En + c];
        }
        __syncthreads();
        const int w = tid >> 6, l = tid & 63;
        const int mt = (w >> 1) * 32, nt = (w & 1) * 32, lr = l & 15, lq = l >> 4;
        floatx4 acc[2][2] = {};
        #pragma unroll
        for (int ks = 0; ks < 64; ks += 32) {
            bf16x8 a0 = ldsfrag(&As1[mt + lr][ks + lq * 8]);
            bf16x8 a1 = ldsfrag(&As1[mt + 16 + lr][ks + lq * 8]);
            bf16x8 b0 = ldsfrag(&Bs1[nt + lr][ks + lq * 8]);
            bf16x8 b1 = ldsfrag(&Bs1[nt + 16 + lr][ks + lq * 8]);
            acc[0][0] = MFMA(a0, b0, acc[0][0]);
            acc[0][1] = MFMA(a0, b1, acc[0][1]);
            acc[1][0] = MFMA(a1, b0, acc[1][0]);
            acc[1][1] = MFMA(a1, b1, acc[1][1]);
        }
        #pragma unroll
        for (int mi = 0; mi < 2; ++mi)
            #pragma unroll
            for (int ni = 0; ni < 2; ++ni)
                #pragma unroll
                for (int ri = 0; ri < 4; ++ri) {
                    int ro = mt + mi * 16 + lq * 4 + ri;
                    int d = d0 + nt + ni * 16 + lr;
                    Out[(size_t)(h * En + ro) * Dn + d] = f2bf(acc[mi][ni][ri] * SCALE);
                }
    } else {                                    // prep_bias
        #pragma unroll
        for (int it = 0; it < 2; ++it) {
            int i = it * 256 + tid;
            biascat[i]       = bf2f(bskc[i]);
            biascat[512 + i] = bf2f(bzc[i]);
            int h = i >> 6, ro = i & 63;
            float s = 0.f;
            for (int e = 0; e < 64; ++e)
                s += bf2f(bqc[h * En + e]) * bf2f(RPc[(size_t)ro * Dn + h * En + e]);
            biascat[1024 + i] = s * SCALE;
        }
    }
}

// ---- R8-exact shared 128x128x512 K-loop, conflict-free swizzle ----
DEV void kloop128(const ushort* __restrict__ Ag, const ushort* __restrict__ Bg,
                  int m0, int n0, ushort* As, ushort* Bs, int tid,
                  floatx4 (&acc)[4][4]) {
    const int w = tid >> 6, l = tid & 63;
    const int mt = (w >> 1) * 64, nt = (w & 1) * 64;
    const int lr = l & 15, lq = l >> 4;
    for (int kc = 0; kc < Dn; kc += 64) {
        __syncthreads();
        #pragma unroll
        for (int j = 0; j < 4; ++j) {
            int slot = (w * 4 + j) * 64 + l;
            int row = slot >> 3;
            int c = ((slot & 7) - row) & 7;
            gload16(&Ag[(size_t)(m0 + row) * Dn + kc + c * 8], &As[(w * 4 + j) * 512]);
            gload16(&Bg[(size_t)(n0 + row) * Dn + kc + c * 8], &Bs[(w * 4 + j) * 512]);
        }
        __syncthreads();
        #pragma unroll
        for (int ks = 0; ks < 64; ks += 32) {
            bf16x8 a[4], bb[4];
            const int cc = (ks >> 3) + lq;
            #pragma unroll
            for (int i = 0; i < 4; ++i) {
                int row = mt + 16 * i + lr;
                a[i] = ldsfrag(&As[(row * 8 + ((cc + row) & 7)) * 8]);
            }
            #pragma unroll
            for (int i = 0; i < 4; ++i) {
                int row = nt + 16 * i + lr;
                bb[i] = ldsfrag(&Bs[(row * 8 + ((cc + row) & 7)) * 8]);
            }
            #pragma unroll
            for (int mi = 0; mi < 4; ++mi)
                #pragma unroll
                for (int ni = 0; ni < 4; ++ni)
                    acc[mi][ni] = MFMA(a[mi], bb[ni], acc[mi][ni]);
        }
    }
}

// ---- big_k: gemm_fused (1536 blocks) || rscore_gemm (512 blocks), 3:1 ----
__global__ __launch_bounds__(256)
void big_k(const ushort* __restrict__ X, const ushort* __restrict__ Wtcat,
           const float* __restrict__ biascat, const ushort* __restrict__ Wkr,
           ushort* __restrict__ skip, ushort* __restrict__ z,
           ushort* __restrict__ qs, ushort* __restrict__ E,
           float* __restrict__ lsum) {
    __shared__ __align__(16) ushort As[8192];
    __shared__ __align__(16) ushort Bs[8192];
    const int bid = blockIdx.x, tid = threadIdx.x;
    const int w = tid >> 6, l = tid & 63;
    const int mt = (w >> 1) * 64, nt = (w & 1) * 64;
    const int lr = l & 15, lq = l >> 4;
    floatx4 acc[4][4] = {};
    if ((bid & 3) != 3) {                       // ---- projection GEMM ----
        int idx = (bid >> 2) * 3 + (bid & 3);   // 0..1535
        const int n0 = (idx % 12) * 128;
        const int m0 = (idx / 12) * 128;
        kloop128(X, Wtcat, m0, n0, As, Bs, tid, acc);
        const int sec = n0 >> 9;                // 0=skip 1=z 2=qs
        ushort* dst = sec == 0 ? skip : (sec == 1 ? z : qs);
        #pragma unroll
        for (int ni = 0; ni < 4; ++ni) {
            int ng = n0 + nt + ni * 16 + lr;
            float bbv = biascat[ng];
            int nc = ng & 511;
            #pragma unroll
            for (int mi = 0; mi < 4; ++mi)
                #pragma unroll
                for (int ri = 0; ri < 4; ++ri) {
                    int row = m0 + mt + mi * 16 + lq * 4 + ri;
                    float v = acc[mi][ni][ri] + bbv;
                    if (sec == 1) v = v / (1.0f + __expf(-v));
                    dst[(size_t)row * Dn + nc] = f2bf(v);
                }
        }
    } else {                                    // ---- router scores GEMM ----
        int idx = bid >> 2;                     // 0..511
        const int n0 = (idx & 127) * 128;       // x row = b*4096+s
        const int m0 = (idx >> 7) * 128;        // Wkr row = h*64+r
        kloop128(Wkr, X, m0, n0, As, Bs, tid, acc);
        const int b = n0 >> 12;
        const int sbase = (n0 & 4095) + nt;
        #pragma unroll
        for (int mi = 0; mi < 4; ++mi)
            #pragma unroll
            for (int ri = 0; ri < 4; ++ri) {
                size_t row = (size_t)(b * 512 + m0 + mt + mi * 16 + lq * 4 + ri);
                float rs = 0.f;
                #pragma unroll
                for (int ni = 0; ni < 4; ++ni) {
                    int s = sbase + ni * 16 + lr;
                    float e = __expf(acc[mi][ni][ri]);
                    E[row * Sn + s] = f2bf(e);
                    rs += e;
                }
                rs += __shfl_xor(rs, 1); rs += __shfl_xor(rs, 2);
                rs += __shfl_xor(rs, 4); rs += __shfl_xor(rs, 8);
                if (lr == 0) atomicAdd(&lsum[row], rs);
            }
    }
}

// ---- rV[bh][r][e] += sum_s rope(E/l)[r][s] * v[s][e]; 2 chunks/block ----
__global__ __launch_bounds__(256)
void router_v_k(const ushort* __restrict__ E, const float* __restrict__ lsum,
                const ushort* __restrict__ X, const float2* __restrict__ tab_jp,
                float* __restrict__ rV) {
    __shared__ ushort As[64][136];   // rope(E/l)[r][s0..127]
    __shared__ ushort Bs[64][136];   // v^T[e][s]
    __shared__ float invl[64];
    const int tid = threadIdx.x;
    const int bh = blockIdx.y, b = bh >> 3, h = bh & 7;
    const int s0 = blockIdx.x * 256;
    const int w = tid >> 6, l = tid & 63;
    const int mt = (w >> 1) * 32, nt = (w & 1) * 32, lr = l & 15, lq = l >> 4;
    if (tid < 64) invl[tid] = 1.0f / lsum[(size_t)bh * Rn + tid];
    __syncthreads();
    floatx4 acc[2][2] = {};
    for (int c = 0; c < 2; ++c) {
        const int sb = s0 + c * 128;
        if (c) __syncthreads();                 // all waves done with chunk c-1
        #pragma unroll
        for (int it = 0; it < 4; ++it) {        // rope staging: 4 s per thread
            int lin = it * 256 + tid;
            int j = lin >> 5, sq = (lin & 31) * 4, sg = sb + sq;
            const ushort* ep = &E[((size_t)bh * Rn + 2 * j) * Sn + sg];
            uint2 ue = *(const uint2*)ep;
            uint2 uo = *(const uint2*)(ep + Sn);
            float4 t01 = *(const float4*)&tab_jp[(size_t)j * Sn + sg];
            float4 t23 = *(const float4*)&tab_jp[(size_t)j * Sn + sg + 2];
            float il_e = invl[2 * j], il_o = invl[2 * j + 1];
            float pe0 = bf2f((ushort)(ue.x & 0xffff)) * il_e;
            float pe1 = bf2f((ushort)(ue.x >> 16)) * il_e;
            float pe2 = bf2f((ushort)(ue.y & 0xffff)) * il_e;
            float pe3 = bf2f((ushort)(ue.y >> 16)) * il_e;
            float po0 = bf2f((ushort)(uo.x & 0xffff)) * il_o;
            float po1 = bf2f((ushort)(uo.x >> 16)) * il_o;
            float po2 = bf2f((ushort)(uo.y & 0xffff)) * il_o;
            float po3 = bf2f((ushort)(uo.y >> 16)) * il_o;
            ushort re[4], ro[4];
            re[0] = f2bf(pe0 * t01.x - po0 * t01.y);
            ro[0] = f2bf(pe0 * t01.y + po0 * t01.x);
            re[1] = f2bf(pe1 * t01.z - po1 * t01.w);
            ro[1] = f2bf(pe1 * t01.w + po1 * t01.z);
            re[2] = f2bf(pe2 * t23.x - po2 * t23.y);
            ro[2] = f2bf(pe2 * t23.y + po2 * t23.x);
            re[3] = f2bf(pe3 * t23.z - po3 * t23.w);
            ro[3] = f2bf(pe3 * t23.w + po3 * t23.z);
            *(uint2*)&As[2 * j][sq]     = *(uint2*)re;
            *(uint2*)&As[2 * j + 1][sq] = *(uint2*)ro;
        }
        #pragma unroll
        for (int it = 0; it < 4; ++it) {        // v^T staging, uint4 loads
            int lin = it * 256 + tid;
            int s = lin >> 3, eg = (lin & 7) * 8;
            ushort u8[8];
            *(uint4*)u8 = *(const uint4*)&X[(size_t)(b * Ln + sb + s) * Dn + h * En + eg];
            #pragma unroll
            for (int t = 0; t < 8; ++t) Bs[eg + t][s] = u8[t];
        }
        __syncthreads();
        #pragma unroll
        for (int ks = 0; ks < 128; ks += 32) {
            bf16x8 a0 = ldsfrag(&As[mt + lr][ks + lq * 8]);
            bf16x8 a1 = ldsfrag(&As[mt + 16 + lr][ks + lq * 8]);
            bf16x8 b0 = ldsfrag(&Bs[nt + lr][ks + lq * 8]);
            bf16x8 b1 = ldsfrag(&Bs[nt + 16 + lr][ks + lq * 8]);
            acc[0][0] = MFMA(a0, b0, acc[0][0]);
            acc[0][1] = MFMA(a0, b1, acc[0][1]);
            acc[1][0] = MFMA(a1, b0, acc[1][0]);
            acc[1][1] = MFMA(a1, b1, acc[1][1]);
        }
    }
    #pragma unroll
    for (int mi = 0; mi < 2; ++mi)
        #pragma unroll
        for (int ni = 0; ni < 2; ++ni)
            #pragma unroll
            for (int ri = 0; ri < 4; ++ri) {
                int r = mt + mi * 16 + lq * 4 + ri;
                int e = nt + ni * 16 + lr;
                atomicAdd(&rV[((size_t)bh * Rn + r) * En + e], acc[mi][ni][ri]);
            }
}

// ---- fused query path: qs -> in-thread softmax -> rope -> @rV -> (+skip)*z ----
__global__ __launch_bounds__(256)
void final_attn_k(const ushort* __restrict__ QS, const float* __restrict__ rV,
                  const float2* __restrict__ tab_pj, const ushort* __restrict__ Skip,
                  const ushort* __restrict__ Zs, const int* __restrict__ flagp,
                  int fhost, void* __restrict__ Outv) {
    __shared__ ushort Ap[64][72];
    __shared__ ushort BvT[64][72];
    __shared__ float Cs[64][68];
    const int f = (fhost >= 0) ? fhost : *flagp;
    const int tid = threadIdx.x;
    const int h = blockIdx.y, b = blockIdx.z, bh = b * Hn + h;
    const int l0 = blockIdx.x * 64;
    const int w = tid >> 6, l = tid & 63;
    const int mt = (w >> 1) * 32, nt = (w & 1) * 32, lr = l & 15, lq = l >> 4;
    #pragma unroll
    for (int i = 0; i < 16; ++i) {
        int lin = i * 256 + tid, r = lin >> 6, e = lin & 63;
        BvT[e][r] = f2bf(rV[((size_t)bh * Rn + r) * En + e]);
    }
    {   // quad-per-token softmax + rope
        const int lt = tid >> 2, qd = tid & 3;
        const ushort* qrow = &QS[(size_t)(b * Ln + l0 + lt) * Dn + h * En + qd * 16];
        uint4 u0 = ((const uint4*)qrow)[0];
        uint4 u1 = ((const uint4*)qrow)[1];
        uint uw[8] = {u0.x, u0.y, u0.z, u0.w, u1.x, u1.y, u1.z, u1.w};
        float p[16];
        float s = 0.f;
        #pragma unroll
        for (int j = 0; j < 8; ++j) {
            float flo = __uint_as_float(uw[j] << 16);
            float fhi = __uint_as_float(uw[j] & 0xffff0000u);
            float e0 = __expf(flo), e1 = __expf(fhi);
            p[2 * j] = e0; p[2 * j + 1] = e1;
            s += e0 + e1;
        }
        s += __shfl_xor(s, 1);
        s += __shfl_xor(s, 2);
        float inv = 1.0f / s;
        #pragma unroll
        for (int u = 0; u < 8; ++u) {
            float A0 = p[2 * u] * inv, A1 = p[2 * u + 1] * inv;
            float2 cs = tab_pj[(l0 + lt) * 32 + qd * 8 + u];
            Ap[lt][qd * 16 + 2 * u]     = f2bf(A0 * cs.x - A1 * cs.y);
            Ap[lt][qd * 16 + 2 * u + 1] = f2bf(A0 * cs.y + A1 * cs.x);
        }
    }
    __syncthreads();
    floatx4 acc[2][2] = {};
    #pragma unroll
    for (int ks = 0; ks < 64; ks += 32) {
        bf16x8 a0 = ldsfrag(&Ap[mt + lr][ks + lq * 8]);
        bf16x8 a1 = ldsfrag(&Ap[mt + 16 + lr][ks + lq * 8]);
        bf16x8 b0 = ldsfrag(&BvT[nt + lr][ks + lq * 8]);
        bf16x8 b1 = ldsfrag(&BvT[nt + 16 + lr][ks + lq * 8]);
        acc[0][0] = MFMA(a0, b0, acc[0][0]);
        acc[0][1] = MFMA(a0, b1, acc[0][1]);
        acc[1][0] = MFMA(a1, b0, acc[1][0]);
        acc[1][1] = MFMA(a1, b1, acc[1][1]);
    }
    #pragma unroll
    for (int mi = 0; mi < 2; ++mi)
        #pragma unroll
        for (int ni = 0; ni < 2; ++ni)
            #pragma unroll
            for (int ri = 0; ri < 4; ++ri)
                Cs[mt + mi * 16 + lq * 4 + ri][nt + ni * 16 + lr] = acc[mi][ni][ri];
    __syncthreads();
    {   // vectorized epilogue: thread = (token, 16-e group)
        const int token = tid >> 2, e0 = (tid & 3) * 16;
        size_t base = (size_t)(b * Ln + l0 + token) * Dn + h * En + e0;
        uint4 sk0 = *(const uint4*)&Skip[base];
        uint4 sk1 = *(const uint4*)&Skip[base + 8];
        uint4 zz0 = *(const uint4*)&Zs[base];
        uint4 zz1 = *(const uint4*)&Zs[base + 8];
        uint sks[8] = {sk0.x, sk0.y, sk0.z, sk0.w, sk1.x, sk1.y, sk1.z, sk1.w};
        uint zzs[8] = {zz0.x, zz0.y, zz0.z, zz0.w, zz1.x, zz1.y, zz1.z, zz1.w};
        float ov[16];
        #pragma unroll
        for (int j = 0; j < 8; ++j) {
            float s0 = __uint_as_float(sks[j] << 16);
            float s1 = __uint_as_float(sks[j] & 0xffff0000u);
            float z0 = __uint_as_float(zzs[j] << 16);
            float z1 = __uint_as_float(zzs[j] & 0xffff0000u);
            ov[2 * j]     = (Cs[token][e0 + 2 * j] + s0) * z0;
            ov[2 * j + 1] = (Cs[token][e0 + 2 * j + 1] + s1) * z1;
        }
        if (f) {
            float* op = (float*)Outv + base;
            #pragma unroll
            for (int q = 0; q < 4; ++q)
                *(float4*)(op + 4 * q) = make_float4(ov[4 * q], ov[4 * q + 1],
                                                     ov[4 * q + 2], ov[4 * q + 3]);
        } else {
            ushort o16[16];
            #pragma unroll
            for (int t = 0; t < 16; ++t) o16[t] = f2bf(ov[t]);
            *(uint4*)((ushort*)Outv + base)     = *(uint4*)o16;
            *(uint4*)((ushort*)Outv + base + 8) = *(uint4*)(o16 + 8);
        }
    }
}

extern "C" void kernel_launch(void* const* d_in, const int* in_sizes, int n_in,
                              void* d_out, int out_size, void* d_ws, size_t ws_size,
                              hipStream_t stream) {
    const size_t OFF_SK    = 0;                  // 16 MiB bf16 [16384][512]
    const size_t OFF_Z     = 16777216;
    const size_t OFF_QS    = 33554432;
    const size_t OFF_E     = 50331648;           // 16 MiB bf16 E
    const size_t OFF_RV    = 67108864;           // 512 KiB f32
    const size_t OFF_L     = 67633152;           // 8 KiB f32 lsum
    const size_t OFF_TAB   = 67641344;           // 1 MiB tab_pj
    const size_t OFF_TABJP = 68689920;           // 1 MiB tab_jp
    const size_t OFF_WT    = 69738496;           // Wtcat 1536x512 bf16 = 1.5 MiB
    const size_t OFF_WKR   = 71311360;           // 512x512 bf16
    const size_t OFF_BIAS  = 71835648;           // 1536 f32
    const size_t OFF_CANON = 71841792;           // 18,944,000 B
    const size_t OFF_FLAG  = OFF_CANON + 18944000;
    const size_t NEED      = OFF_FLAG + 16;      // ~90.8 MB
    if (ws_size < NEED) return;

    char* ws = (char*)d_ws;
    ushort* skip  = (ushort*)(ws + OFF_SK);
    ushort* z     = (ushort*)(ws + OFF_Z);
    ushort* qs    = (ushort*)(ws + OFF_QS);
    ushort* E     = (ushort*)(ws + OFF_E);
    float*  rV    = (float*)(ws + OFF_RV);
    float*  lsum  = (float*)(ws + OFF_L);
    float2* tabpj = (float2*)(ws + OFF_TAB);
    float2* tabjp = (float2*)(ws + OFF_TABJP);
    ushort* Wtcat = (ushort*)(ws + OFF_WT);
    ushort* Wkr   = (ushort*)(ws + OFF_WKR);
    float*  bias  = (float*)(ws + OFF_BIAS);
    ushort* canon = (ushort*)(ws + OFF_CANON);
    int*    flag  = (int*)(ws + OFF_FLAG);

    const ushort* Xc   = canon;
    const ushort* Wqc  = canon + SEG1;
    const ushort* bqc  = canon + SEG2;
    const ushort* Wkc  = canon + SEG3;
    const ushort* Wskc = canon + SEG5;
    const ushort* bskc = canon + SEG6;
    const ushort* Wzc  = canon + SEG7;
    const ushort* bzc  = canon + SEG8;
    const ushort* RPc  = canon + SEG9;

    // host-side dtype detection: x is (4,4096,512) -> f32 = 33554432 B,
    // bf16 = 16777216 B. Fall back to the device sniffer if ambiguous.
    int mode = -1;
    if (in_sizes && n_in > 0) {
        if (in_sizes[0] == 33554432) mode = 1;
        else if (in_sizes[0] == 16777216) mode = 0;
    }
    if (mode < 0) {
        if (out_size == 33554432) mode = 1;
        else if (out_size == 16777216) mode = 0;
    }
    if (mode < 0)
        sniff_k<<<1, 256, 0, stream>>>((const uint*)d_in[0], flag);

    prep0_k<<<5268, 256, 0, stream>>>(d_in[0], d_in[1], d_in[2], d_in[3], d_in[4],
                                      d_in[5], d_in[6], d_in[7], d_in[8], d_in[9],
                                      flag, mode, canon, tabpj, tabjp, rV, lsum);
    prep1_k<<<257, 256, 0, stream>>>(Wskc, Wzc, Wqc, Wkc, RPc, bqc, bskc, bzc,
                                     Wtcat, Wkr, bias);
    big_k<<<2048, 256, 0, stream>>>(Xc, Wtcat, bias, Wkr, skip, z, qs, E, lsum);
    router_v_k<<<dim3(16, 32), 256, 0, stream>>>(E, lsum, Xc, tabjp, rV);
    final_attn_k<<<dim3(64, 8, 4), 256, 0, stream>>>(qs, rV, tabpj, skip, z, flag,
                                                     mode, d_out);
}

// Round 9
// 194.150 us; speedup vs baseline: 1.2681x; 1.0620x over previous
//
#include <hip/hip_runtime.h>

// RouterAttention on gfx950. B=4 L=S=4096 D=512 H=8 E=R=64.
// R15 (best, 206.2us): 128^2 2-barrier big_k=77us pinned; tail ~128us at floors.
// R16: unified 256^2 counted-vmcnt big_k:
//  - ONE GEMM C[16384][2048] = X @ [Wtcat||Wkr]^T (contiguous in ws).
//  - E stored s-major [16384][512] (coalesced epilogue); router_v staging
//    rewritten for s-major E + tab_pj; tab_jp deleted.
//  - LDS 128KB = 2buf x 2khalf x ([256][32] A + B). K-half split => landing
//    order == need order => counted vmcnt(4) works (never 0 in steady state).
//  - 4 phases/K-tile: stage (t+1){Ak0,Bk0,Ak1,Bk1} at p0..p3; vmcnt(4)+bar
//    at boundary (need Ak0,Bk0) and mid (need Ak1,Bk1). ~800cy cover/load.
//  - rot-4 LDS swizzle (chunk p holds k-chunk (p-row/2)&3): 2-way banks (free),
//    linear gload_lds dest + pre-rotated global source (rule 21).

#define DEV __device__ __forceinline__
#define SCHED_FENCE() __builtin_amdgcn_sched_barrier(0)

constexpr int Bn = 4, Ln = 4096, Dn = 512, Hn = 8, En = 64, Rn = 64;
constexpr int Sn = 4096;
constexpr float SCALE = 0.125f;                 // 1/sqrt(E)
constexpr float L2B_OVER_K = 13.287712379549449f / 32.0f; // log2(10000)/32

typedef __bf16 bf16x8 __attribute__((ext_vector_type(8)));
typedef float floatx4 __attribute__((ext_vector_type(4)));

DEV float bf2f(ushort u) { return __uint_as_float(((unsigned)u) << 16); }
DEV ushort f2bf(float f) {
    unsigned u = __float_as_uint(f);
    u += 0x7fffu + ((u >> 16) & 1u);            // RNE
    return (ushort)(u >> 16);
}
DEV bf16x8 ldsfrag(const ushort* p) { return *reinterpret_cast<const bf16x8*>(p); }
#define MFMA(a, b, c) __builtin_amdgcn_mfma_f32_16x16x32_bf16(a, b, c, 0, 0, 0)

DEV void gload16(const ushort* g, ushort* lds) {
    __builtin_amdgcn_global_load_lds(
        (const __attribute__((address_space(1))) unsigned int*)g,
        (__attribute__((address_space(3))) unsigned int*)lds, 16, 0, 0);
}

DEV int wave_sum_i(int v) {
    #pragma unroll
    for (int off = 1; off < 64; off <<= 1) v += __shfl_xor(v, off);
    return v;
}

// ---- dtype sniffer (fallback only): flag=1 if x looks like f32 ----
__global__ __launch_bounds__(256) void sniff_k(const uint* __restrict__ x, int* __restrict__ flag) {
    int t = threadIdx.x, cnt = 0;
    #pragma unroll
    for (int i = 0; i < 16; ++i) {
        uint u = x[t * 16 + i];
        uint e = (u >> 7) & 0xFF;
        cnt += (e >= 100 && e <= 140) ? 1 : 0;
    }
    cnt = wave_sum_i(cnt);
    __shared__ int red[4];
    int w = t >> 6, l = t & 63;
    if (l == 0) red[w] = cnt;
    __syncthreads();
    if (t == 0) flag[0] = ((red[0] + red[1] + red[2] + red[3]) < 2048) ? 1 : 0;
}

constexpr size_t SEG1 = 8388608, SEG2 = 8650752, SEG3 = 8651264, SEG4 = 8913408,
                 SEG5 = 8913920, SEG6 = 9176064, SEG7 = 9176576, SEG8 = 9438720,
                 SEG9 = 9439232, SEGT = 9472000;

// ---- prep0: canon vec8 (4625 blk) + rope tab (512 blk) + zero (131 blk) ----
__global__ __launch_bounds__(256)
void prep0_k(const void* p0, const void* p1, const void* p2, const void* p3,
             const void* p4, const void* p5, const void* p6, const void* p7,
             const void* p8, const void* p9, const int* __restrict__ flag,
             int fhost,
             ushort* __restrict__ dst, float2* __restrict__ tab_pj,
             float* __restrict__ rV, float* __restrict__ lsum) {
    const int bid = blockIdx.x, tid = threadIdx.x;
    if (bid < 4625) {                           // canon: 8 elems/thread
        const int f = (fhost >= 0) ? fhost : *flag;
        size_t i = ((size_t)bid * 256 + tid) * 8;   // all SEG bounds %8==0
        const void* sp; size_t off;
        if      (i < SEG1) { sp = p0; off = i; }
        else if (i < SEG2) { sp = p1; off = i - SEG1; }
        else if (i < SEG3) { sp = p2; off = i - SEG2; }
        else if (i < SEG4) { sp = p3; off = i - SEG3; }
        else if (i < SEG5) { sp = p4; off = i - SEG4; }
        else if (i < SEG6) { sp = p5; off = i - SEG5; }
        else if (i < SEG7) { sp = p6; off = i - SEG6; }
        else if (i < SEG8) { sp = p7; off = i - SEG7; }
        else if (i < SEG9) { sp = p8; off = i - SEG8; }
        else               { sp = p9; off = i - SEG9; }
        ushort o8[8];
        if (f) {
            float4 a = *((const float4*)((const float*)sp + off));
            float4 b = *((const float4*)((const float*)sp + off) + 1);
            o8[0] = f2bf(a.x); o8[1] = f2bf(a.y); o8[2] = f2bf(a.z); o8[3] = f2bf(a.w);
            o8[4] = f2bf(b.x); o8[5] = f2bf(b.y); o8[6] = f2bf(b.z); o8[7] = f2bf(b.w);
        } else {
            *(uint4*)o8 = *(const uint4*)((const ushort*)sp + off);
        }
        *(uint4*)&dst[i] = *(uint4*)o8;
    } else if (bid < 5137) {                    // rope table [p][j]
        int idx = (bid - 4625) * 256 + tid;     // 131072 entries
        int p = idx >> 5, j = idx & 31;
        float theta = exp2f(-(float)j * L2B_OVER_K);
        float ang = (float)(Sn - 1 - p) * theta;
        float s, c;
        sincosf(ang, &s, &c);
        tab_pj[idx] = make_float2(c, s);
    } else {                                    // zero rV + lsum
        int base = (bid - 5137) * 1024 + tid;
        #pragma unroll
        for (int r = 0; r < 4; ++r) {
            int f32i = base + r * 256;
            if (f32i < 131072) rV[f32i] = 0.f;
            else if (f32i < 133120) lsum[f32i - 131072] = 0.f;
        }
    }
}

// ---- prep1: 2 transposes (128 blk) + prep_wr (128 blk) + prep_bias (1 blk) ----
__global__ __launch_bounds__(256)
void prep1_k(const ushort* __restrict__ Wskc, const ushort* __restrict__ Wzc,
             const ushort* __restrict__ Wqc, const ushort* __restrict__ Wkc,
             const ushort* __restrict__ RPc, const ushort* __restrict__ bqc,
             const ushort* __restrict__ bskc, const ushort* __restrict__ bzc,
             ushort* __restrict__ Wtcat, ushort* __restrict__ Wkr,
             float* __restrict__ biascat) {
    __shared__ ushort t64[64][65];
    __shared__ ushort As1[64][72];
    __shared__ ushort Bs1[64][72];
    const int bid = blockIdx.x, tid = threadIdx.x;
    if (bid < 128) {                            // transpose: Wt[dout][din]
        const ushort* W = (bid < 64) ? Wskc : Wzc;
        ushort* Wt = Wtcat + (bid < 64 ? 0 : 262144);
        int bb = bid & 63;
        int bx = (bb & 7) * 64, by = (bb >> 3) * 64;
        int c = tid & 63, r0 = (tid >> 6) * 16;
        #pragma unroll
        for (int i = 0; i < 16; ++i) t64[r0 + i][c] = W[(size_t)(by + r0 + i) * Dn + bx + c];
        __syncthreads();
        #pragma unroll
        for (int i = 0; i < 16; ++i) Wt[(size_t)(bx + r0 + i) * Dn + by + c] = t64[c][r0 + i];
    } else if (bid < 256) {                     // prep_wr
        int idx = bid - 128;
        int zsel = idx >> 6, rem = idx & 63;
        int d0 = (rem & 7) * 64, h = rem >> 3;
        const ushort* W = zsel ? Wkc : Wqc;
        ushort* Out = zsel ? Wkr : (Wtcat + 524288);
        #pragma unroll
        for (int j = 0; j < 2; ++j) {
            int lin = j * 256 + tid, row = lin >> 3, c = (lin & 7) * 8;
            *(uint4*)&As1[row][c] = *(const uint4*)&RPc[(size_t)row * Dn + h * En + c];
            *(uint4*)&Bs1[row][c] = *(const uint4*)&W[(size_t)(d0 + row) * Dn + h * En + c];
        }
        __syncthreads();
        const int w = tid >> 6, l = tid & 63;
        const int mt = (w >> 1) * 32, nt = (w & 1) * 32, lr = l & 15, lq = l >> 4;
        floatx4 acc[2][2] = {};
        #pragma unroll
        for (int ks = 0; ks < 64; ks += 32) {
            bf16x8 a0 = ldsfrag(&As1[mt + lr][ks + lq * 8]);
            bf16x8 a1 = ldsfrag(&As1[mt + 16 + lr][ks + lq * 8]);
            bf16x8 b0 = ldsfrag(&Bs1[nt + lr][ks + lq * 8]);
            bf16x8 b1 = ldsfrag(&Bs1[nt + 16 + lr][ks + lq * 8]);
            acc[0][0] = MFMA(a0, b0, acc[0][0]);
            acc[0][1] = MFMA(a0, b1, acc[0][1]);
            acc[1][0] = MFMA(a1, b0, acc[1][0]);
            acc[1][1] = MFMA(a1, b1, acc[1][1]);
        }
        #pragma unroll
        for (int mi = 0; mi < 2; ++mi)
            #pragma unroll
            for (int ni = 0; ni < 2; ++ni)
                #pragma unroll
                for (int ri = 0; ri < 4; ++ri) {
                    int ro = mt + mi * 16 + lq * 4 + ri;
                    int d = d0 + nt + ni * 16 + lr;
                    Out[(size_t)(h * En + ro) * Dn + d] = f2bf(acc[mi][ni][ri] * SCALE);
                }
    } else {                                    // prep_bias
        #pragma unroll
        for (int it = 0; it < 2; ++it) {
            int i = it * 256 + tid;
            biascat[i]       = bf2f(bskc[i]);
            biascat[512 + i] = bf2f(bzc[i]);
            int h = i >> 6, ro = i & 63;
            float s = 0.f;
            for (int e = 0; e < 64; ++e)
                s += bf2f(bqc[h * En + e]) * bf2f(RPc[(size_t)ro * Dn + h * En + e]);
            biascat[1024 + i] = s * SCALE;
        }
    }
}

// ---- 256^2 big_k pieces: k-half-tile [256 rows][32 k], rot-4 swizzle ----
// LDS chunk p (of 4 x 8-ushort) of row r holds global k-chunk (p - (r>>1))&3.
// Stage: 512 thr x 2 gload16 = 16KB; lane addr linear (slot*16B).
DEV void stage_half(const ushort* __restrict__ G, int r0, int kb,
                    ushort* Ldst, int w, int l) {
    #pragma unroll
    for (int j = 0; j < 2; ++j) {
        int slot = (w * 2 + j) * 64 + l;
        int row = slot >> 2, p = slot & 3;
        int g = (p - (row >> 1)) & 3;
        gload16(&G[(size_t)(r0 + row) * Dn + kb + g * 8],
                Ldst + (w * 2 + j) * 512);
    }
}
DEV bf16x8 rdfrag(const ushort* tile, int row, int lq) {
    int p = (lq + (row >> 1)) & 3;
    return ldsfrag(tile + row * 32 + p * 8);
}

// ---- big_k: C[16384][2048] = X @ Wcat^T; 512 blocks x 512 thr ----
__global__ __launch_bounds__(512)
void big_k(const ushort* __restrict__ X, const ushort* __restrict__ Wcat,
           const float* __restrict__ biascat,
           ushort* __restrict__ skip, ushort* __restrict__ z,
           ushort* __restrict__ qs, ushort* __restrict__ E,
           float* __restrict__ lsum) {
    __shared__ __align__(16) ushort As[2][2][8192];   // [buf][khalf][256x32]
    __shared__ __align__(16) ushort Bs[2][2][8192];
    const int tid = threadIdx.x;
    const int w = tid >> 6, l = tid & 63;
    const int wm = w >> 2, wn = w & 3;
    const int lr = l & 15, lq = l >> 4;
    const int swz = ((int)blockIdx.x & 7) * 64 + ((int)blockIdx.x >> 3); // XCD chunk
    const int bm = (swz >> 3) * 256, nb = (swz & 7) * 256;
    floatx4 acc[8][4] = {};
    // prologue: K-tile 0's 4 half-tiles (issue order Ak0,Bk0,Ak1,Bk1)
    stage_half(X,    bm, 0,  &As[0][0][0], w, l);
    stage_half(Wcat, nb, 0,  &Bs[0][0][0], w, l);
    stage_half(X,    bm, 32, &As[0][1][0], w, l);
    stage_half(Wcat, nb, 32, &Bs[0][1][0], w, l);
    #pragma unroll
    for (int t = 0; t < 8; ++t) {
        const int cur = t & 1, nxt = cur ^ 1;
        const int kb1 = (t + 1) * 64;
        // boundary: need (t)Ak0,Bk0 landed; (t)Ak1,Bk1 (newest 4 loads) may fly
        asm volatile("s_waitcnt vmcnt(4)" ::: "memory");
        SCHED_FENCE();
        asm volatile("s_waitcnt lgkmcnt(0)" ::: "memory");
        SCHED_FENCE();
        __builtin_amdgcn_s_barrier();
        SCHED_FENCE();
        bf16x8 af[8], b0, b1;
        // p0: stage (t+1)Ak0; compute kh0 x n{0,1}
        if (t < 7) stage_half(X, bm, kb1, &As[nxt][0][0], w, l);
        #pragma unroll
        for (int i = 0; i < 8; ++i)
            af[i] = rdfrag(&As[cur][0][0], wm * 128 + i * 16 + lr, lq);
        b0 = rdfrag(&Bs[cur][0][0], wn * 64 + lr, lq);
        b1 = rdfrag(&Bs[cur][0][0], wn * 64 + 16 + lr, lq);
        __builtin_amdgcn_s_setprio(1);
        #pragma unroll
        for (int i = 0; i < 8; ++i) {
            acc[i][0] = MFMA(af[i], b0, acc[i][0]);
            acc[i][1] = MFMA(af[i], b1, acc[i][1]);
        }
        __builtin_amdgcn_s_setprio(0);
        // p1: stage (t+1)Bk0; compute kh0 x n{2,3} (A cached)
        if (t < 7) stage_half(Wcat, nb, kb1, &Bs[nxt][0][0], w, l);
        b0 = rdfrag(&Bs[cur][0][0], wn * 64 + 32 + lr, lq);
        b1 = rdfrag(&Bs[cur][0][0], wn * 64 + 48 + lr, lq);
        __builtin_amdgcn_s_setprio(1);
        #pragma unroll
        for (int i = 0; i < 8; ++i) {
            acc[i][2] = MFMA(af[i], b0, acc[i][2]);
            acc[i][3] = MFMA(af[i], b1, acc[i][3]);
        }
        __builtin_amdgcn_s_setprio(0);
        // mid: need (t)Ak1,Bk1 landed ((t+1)Ak0,Bk0 may fly)
        if (t < 7) { asm volatile("s_waitcnt vmcnt(4)" ::: "memory"); }
        else       { asm volatile("s_waitcnt vmcnt(0)" ::: "memory"); }
        SCHED_FENCE();
        asm volatile("s_waitcnt lgkmcnt(0)" ::: "memory");
        SCHED_FENCE();
        __builtin_amdgcn_s_barrier();
        SCHED_FENCE();
        // p2: stage (t+1)Ak1; compute kh1 x n{0,1}
        if (t < 7) stage_half(X, bm, kb1 + 32, &As[nxt][1][0], w, l);
        #pragma unroll
        for (int i = 0; i < 8; ++i)
            af[i] = rdfrag(&As[cur][1][0], wm * 128 + i * 16 + lr, lq);
        b0 = rdfrag(&Bs[cur][1][0], wn * 64 + lr, lq);
        b1 = rdfrag(&Bs[cur][1][0], wn * 64 + 16 + lr, lq);
        __builtin_amdgcn_s_setprio(1);
        #pragma unroll
        for (int i = 0; i < 8; ++i) {
            acc[i][0] = MFMA(af[i], b0, acc[i][0]);
            acc[i][1] = MFMA(af[i], b1, acc[i][1]);
        }
        __builtin_amdgcn_s_setprio(0);
        // p3: stage (t+1)Bk1; compute kh1 x n{2,3}
        if (t < 7) stage_half(Wcat, nb, kb1 + 32, &Bs[nxt][1][0], w, l);
        b0 = rdfrag(&Bs[cur][1][0], wn * 64 + 32 + lr, lq);
        b1 = rdfrag(&Bs[cur][1][0], wn * 64 + 48 + lr, lq);
        __builtin_amdgcn_s_setprio(1);
        #pragma unroll
        for (int i = 0; i < 8; ++i) {
            acc[i][2] = MFMA(af[i], b0, acc[i][2]);
            acc[i][3] = MFMA(af[i], b1, acc[i][3]);
        }
        __builtin_amdgcn_s_setprio(0);
    }
    // ---- epilogue (out of K-loop, acc in regs) ----
    const int sec = nb >> 9;                    // 0=skip 1=z 2=qs 3=E
    if (sec < 3) {
        ushort* dst = sec == 0 ? skip : (sec == 1 ? z : qs);
        #pragma unroll
        for (int ni = 0; ni < 4; ++ni) {
            int col = nb + wn * 64 + ni * 16 + lr;
            float bbv = biascat[col];
            int nc = col & 511;
            #pragma unroll
            for (int mi = 0; mi < 8; ++mi)
                #pragma unroll
                for (int ri = 0; ri < 4; ++ri) {
                    int row = bm + wm * 128 + mi * 16 + lq * 4 + ri;
                    float v = acc[mi][ni][ri] + bbv;
                    if (sec == 1) v = v / (1.0f + __expf(-v));
                    dst[(size_t)row * Dn + nc] = f2bf(v);
                }
        }
    } else {                                    // E (s-major) + lsum
        const int b = bm >> 12;
        float rs[4] = {0.f, 0.f, 0.f, 0.f};
        #pragma unroll
        for (int ni = 0; ni < 4; ++ni) {
            int hr = (nb - 1536) + wn * 64 + ni * 16 + lr;
            #pragma unroll
            for (int mi = 0; mi < 8; ++mi)
                #pragma unroll
                for (int ri = 0; ri < 4; ++ri) {
                    int row = bm + wm * 128 + mi * 16 + lq * 4 + ri;
                    float e = __expf(acc[mi][ni][ri]);
                    E[(size_t)row * 512 + hr] = f2bf(e);
                    rs[ni] += e;
                }
        }
        #pragma unroll
        for (int ni = 0; ni < 4; ++ni) {
            float r = rs[ni];
            r += __shfl_xor(r, 16);
            r += __shfl_xor(r, 32);
            if (l < 16)
                atomicAdd(&lsum[b * 512 + (nb - 1536) + wn * 64 + ni * 16 + l], r);
        }
    }
}

// ---- rV[bh][r][e] += sum_s rope(E/l)[r][s] * v[s][e]; 2 chunks/block ----
// E is s-major [16384][512]; rope pairs (2j,2j+1) arrive in one uint4.
__global__ __launch_bounds__(256)
void router_v_k(const ushort* __restrict__ E, const float* __restrict__ lsum,
                const ushort* __restrict__ X, const float2* __restrict__ tab_pj,
                float* __restrict__ rV) {
    __shared__ ushort As[64][136];   // rope(E/l)[r][s0..127]
    __shared__ ushort Bs[64][136];   // v^T[e][s]
    __shared__ float invl[64];
    const int tid = threadIdx.x;
    const int bh = blockIdx.y, b = bh >> 3, h = bh & 7;
    const int s0 = blockIdx.x * 256;
    const int w = tid >> 6, l = tid & 63;
    const int mt = (w >> 1) * 32, nt = (w & 1) * 32, lr = l & 15, lq = l >> 4;
    if (tid < 64) invl[tid] = 1.0f / lsum[(size_t)bh * Rn + tid];
    __syncthreads();
    floatx4 acc[2][2] = {};
    for (int c = 0; c < 2; ++c) {
        const int sb = s0 + c * 128;
        if (c) __syncthreads();                 // all waves done with chunk c-1
        #pragma unroll
        for (int it = 0; it < 4; ++it) {        // rope staging: 8 r x 1 s /thr
            int lin = it * 256 + tid;
            int s = lin >> 3, rg = (lin & 7) * 8;
            int gs = sb + s;
            ushort vv[8];
            *(uint4*)vv = *(const uint4*)&E[((size_t)(b * Ln + gs)) * 512 + h * En + rg];
            const float4* tb = (const float4*)&tab_pj[(size_t)gs * 32 + (rg >> 1)];
            float4 t01 = tb[0], t23 = tb[1];
            float c0 = t01.x, s0_ = t01.y, c1 = t01.z, s1_ = t01.w;
            float c2 = t23.x, s2_ = t23.y, c3 = t23.z, s3_ = t23.w;
            float pe0 = bf2f(vv[0]) * invl[rg + 0], po0 = bf2f(vv[1]) * invl[rg + 1];
            float pe1 = bf2f(vv[2]) * invl[rg + 2], po1 = bf2f(vv[3]) * invl[rg + 3];
            float pe2 = bf2f(vv[4]) * invl[rg + 4], po2 = bf2f(vv[5]) * invl[rg + 5];
            float pe3 = bf2f(vv[6]) * invl[rg + 6], po3 = bf2f(vv[7]) * invl[rg + 7];
            As[rg + 0][s] = f2bf(pe0 * c0 - po0 * s0_);
            As[rg + 1][s] = f2bf(pe0 * s0_ + po0 * c0);
            As[rg + 2][s] = f2bf(pe1 * c1 - po1 * s1_);
            As[rg + 3][s] = f2bf(pe1 * s1_ + po1 * c1);
            As[rg + 4][s] = f2bf(pe2 * c2 - po2 * s2_);
            As[rg + 5][s] = f2bf(pe2 * s2_ + po2 * c2);
            As[rg + 6][s] = f2bf(pe3 * c3 - po3 * s3_);
            As[rg + 7][s] = f2bf(pe3 * s3_ + po3 * c3);
        }
        #pragma unroll
        for (int it = 0; it < 4; ++it) {        // v^T staging, uint4 loads
            int lin = it * 256 + tid;
            int s = lin >> 3, eg = (lin & 7) * 8;
            ushort u8[8];
            *(uint4*)u8 = *(const uint4*)&X[(size_t)(b * Ln + sb + s) * Dn + h * En + eg];
            #pragma unroll
            for (int t = 0; t < 8; ++t) Bs[eg + t][s] = u8[t];
        }
        __syncthreads();
        #pragma unroll
        for (int ks = 0; ks < 128; ks += 32) {
            bf16x8 a0 = ldsfrag(&As[mt + lr][ks + lq * 8]);
            bf16x8 a1 = ldsfrag(&As[mt + 16 + lr][ks + lq * 8]);
            bf16x8 b0 = ldsfrag(&Bs[nt + lr][ks + lq * 8]);
            bf16x8 b1 = ldsfrag(&Bs[nt + 16 + lr][ks + lq * 8]);
            acc[0][0] = MFMA(a0, b0, acc[0][0]);
            acc[0][1] = MFMA(a0, b1, acc[0][1]);
            acc[1][0] = MFMA(a1, b0, acc[1][0]);
            acc[1][1] = MFMA(a1, b1, acc[1][1]);
        }
    }
    #pragma unroll
    for (int mi = 0; mi < 2; ++mi)
        #pragma unroll
        for (int ni = 0; ni < 2; ++ni)
            #pragma unroll
            for (int ri = 0; ri < 4; ++ri) {
                int r = mt + mi * 16 + lq * 4 + ri;
                int e = nt + ni * 16 + lr;
                atomicAdd(&rV[((size_t)bh * Rn + r) * En + e], acc[mi][ni][ri]);
            }
}

// ---- fused query path: qs -> in-thread softmax -> rope -> @rV -> (+skip)*z ----
__global__ __launch_bounds__(256)
void final_attn_k(const ushort* __restrict__ QS, const float* __restrict__ rV,
                  const float2* __restrict__ tab_pj, const ushort* __restrict__ Skip,
                  const ushort* __restrict__ Zs, const int* __restrict__ flagp,
                  int fhost, void* __restrict__ Outv) {
    __shared__ ushort Ap[64][72];
    __shared__ ushort BvT[64][72];
    __shared__ float Cs[64][68];
    const int f = (fhost >= 0) ? fhost : *flagp;
    const int tid = threadIdx.x;
    const int h = blockIdx.y, b = blockIdx.z, bh = b * Hn + h;
    const int l0 = blockIdx.x * 64;
    const int w = tid >> 6, l = tid & 63;
    const int mt = (w >> 1) * 32, nt = (w & 1) * 32, lr = l & 15, lq = l >> 4;
    #pragma unroll
    for (int i = 0; i < 16; ++i) {
        int lin = i * 256 + tid, r = lin >> 6, e = lin & 63;
        BvT[e][r] = f2bf(rV[((size_t)bh * Rn + r) * En + e]);
    }
    {   // quad-per-token softmax + rope
        const int lt = tid >> 2, qd = tid & 3;
        const ushort* qrow = &QS[(size_t)(b * Ln + l0 + lt) * Dn + h * En + qd * 16];
        uint4 u0 = ((const uint4*)qrow)[0];
        uint4 u1 = ((const uint4*)qrow)[1];
        uint uw[8] = {u0.x, u0.y, u0.z, u0.w, u1.x, u1.y, u1.z, u1.w};
        float p[16];
        float s = 0.f;
        #pragma unroll
        for (int j = 0; j < 8; ++j) {
            float flo = __uint_as_float(uw[j] << 16);
            float fhi = __uint_as_float(uw[j] & 0xffff0000u);
            float e0 = __expf(flo), e1 = __expf(fhi);
            p[2 * j] = e0; p[2 * j + 1] = e1;
            s += e0 + e1;
        }
        s += __shfl_xor(s, 1);
        s += __shfl_xor(s, 2);
        float inv = 1.0f / s;
        #pragma unroll
        for (int u = 0; u < 8; ++u) {
            float A0 = p[2 * u] * inv, A1 = p[2 * u + 1] * inv;
            float2 cs = tab_pj[(l0 + lt) * 32 + qd * 8 + u];
            Ap[lt][qd * 16 + 2 * u]     = f2bf(A0 * cs.x - A1 * cs.y);
            Ap[lt][qd * 16 + 2 * u + 1] = f2bf(A0 * cs.y + A1 * cs.x);
        }
    }
    __syncthreads();
    floatx4 acc[2][2] = {};
    #pragma unroll
    for (int ks = 0; ks < 64; ks += 32) {
        bf16x8 a0 = ldsfrag(&Ap[mt + lr][ks + lq * 8]);
        bf16x8 a1 = ldsfrag(&Ap[mt + 16 + lr][ks + lq * 8]);
        bf16x8 b0 = ldsfrag(&BvT[nt + lr][ks + lq * 8]);
        bf16x8 b1 = ldsfrag(&BvT[nt + 16 + lr][ks + lq * 8]);
        acc[0][0] = MFMA(a0, b0, acc[0][0]);
        acc[0][1] = MFMA(a0, b1, acc[0][1]);
        acc[1][0] = MFMA(a1, b0, acc[1][0]);
        acc[1][1] = MFMA(a1, b1, acc[1][1]);
    }
    #pragma unroll
    for (int mi = 0; mi < 2; ++mi)
        #pragma unroll
        for (int ni = 0; ni < 2; ++ni)
            #pragma unroll
            for (int ri = 0; ri < 4; ++ri)
                Cs[mt + mi * 16 + lq * 4 + ri][nt + ni * 16 + lr] = acc[mi][ni][ri];
    __syncthreads();
    {   // vectorized epilogue: thread = (token, 16-e group)
        const int token = tid >> 2, e0 = (tid & 3) * 16;
        size_t base = (size_t)(b * Ln + l0 + token) * Dn + h * En + e0;
        uint4 sk0 = *(const uint4*)&Skip[base];
        uint4 sk1 = *(const uint4*)&Skip[base + 8];
        uint4 zz0 = *(const uint4*)&Zs[base];
        uint4 zz1 = *(const uint4*)&Zs[base + 8];
        uint sks[8] = {sk0.x, sk0.y, sk0.z, sk0.w, sk1.x, sk1.y, sk1.z, sk1.w};
        uint zzs[8] = {zz0.x, zz0.y, zz0.z, zz0.w, zz1.x, zz1.y, zz1.z, zz1.w};
        float ov[16];
        #pragma unroll
        for (int j = 0; j < 8; ++j) {
            float s0 = __uint_as_float(sks[j] << 16);
            float s1 = __uint_as_float(sks[j] & 0xffff0000u);
            float z0 = __uint_as_float(zzs[j] << 16);
            float z1 = __uint_as_float(zzs[j] & 0xffff0000u);
            ov[2 * j]     = (Cs[token][e0 + 2 * j] + s0) * z0;
            ov[2 * j + 1] = (Cs[token][e0 + 2 * j + 1] + s1) * z1;
        }
        if (f) {
            float* op = (float*)Outv + base;
            #pragma unroll
            for (int q = 0; q < 4; ++q)
                *(float4*)(op + 4 * q) = make_float4(ov[4 * q], ov[4 * q + 1],
                                                     ov[4 * q + 2], ov[4 * q + 3]);
        } else {
            ushort o16[16];
            #pragma unroll
            for (int t = 0; t < 16; ++t) o16[t] = f2bf(ov[t]);
            *(uint4*)((ushort*)Outv + base)     = *(uint4*)o16;
            *(uint4*)((ushort*)Outv + base + 8) = *(uint4*)(o16 + 8);
        }
    }
}

extern "C" void kernel_launch(void* const* d_in, const int* in_sizes, int n_in,
                              void* d_out, int out_size, void* d_ws, size_t ws_size,
                              hipStream_t stream) {
    const size_t OFF_SK    = 0;                  // 16 MiB bf16 [16384][512]
    const size_t OFF_Z     = 16777216;
    const size_t OFF_QS    = 33554432;
    const size_t OFF_E     = 50331648;           // 16 MiB bf16 E (s-major)
    const size_t OFF_RV    = 67108864;           // 512 KiB f32
    const size_t OFF_L     = 67633152;           // 8 KiB f32 lsum
    const size_t OFF_TAB   = 67641344;           // 1 MiB tab_pj
    const size_t OFF_TABJP = 68689920;           // (unused since R16)
    const size_t OFF_WT    = 69738496;           // Wtcat 1536x512 bf16
    const size_t OFF_WKR   = 71311360;           // 512x512 bf16 (contiguous!)
    const size_t OFF_BIAS  = 71835648;           // 1536 f32
    const size_t OFF_CANON = 71841792;           // 18,944,000 B
    const size_t OFF_FLAG  = OFF_CANON + 18944000;
    const size_t NEED      = OFF_FLAG + 16;      // ~90.8 MB
    if (ws_size < NEED) return;

    char* ws = (char*)d_ws;
    ushort* skip  = (ushort*)(ws + OFF_SK);
    ushort* z     = (ushort*)(ws + OFF_Z);
    ushort* qs    = (ushort*)(ws + OFF_QS);
    ushort* E     = (ushort*)(ws + OFF_E);
    float*  rV    = (float*)(ws + OFF_RV);
    float*  lsum  = (float*)(ws + OFF_L);
    float2* tabpj = (float2*)(ws + OFF_TAB);
    ushort* Wtcat = (ushort*)(ws + OFF_WT);
    ushort* Wkr   = (ushort*)(ws + OFF_WKR);
    float*  bias  = (float*)(ws + OFF_BIAS);
    ushort* canon = (ushort*)(ws + OFF_CANON);
    int*    flag  = (int*)(ws + OFF_FLAG);

    const ushort* Xc   = canon;
    const ushort* Wqc  = canon + SEG1;
    const ushort* bqc  = canon + SEG2;
    const ushort* Wkc  = canon + SEG3;
    const ushort* Wskc = canon + SEG5;
    const ushort* bskc = canon + SEG6;
    const ushort* Wzc  = canon + SEG7;
    const ushort* bzc  = canon + SEG8;
    const ushort* RPc  = canon + SEG9;

    // host-side dtype detection; device sniffer as fallback.
    int mode = -1;
    if (in_sizes && n_in > 0) {
        if (in_sizes[0] == 33554432) mode = 1;
        else if (in_sizes[0] == 16777216) mode = 0;
    }
    if (mode < 0) {
        if (out_size == 33554432) mode = 1;
        else if (out_size == 16777216) mode = 0;
    }
    if (mode < 0)
        sniff_k<<<1, 256, 0, stream>>>((const uint*)d_in[0], flag);

    prep0_k<<<5268, 256, 0, stream>>>(d_in[0], d_in[1], d_in[2], d_in[3], d_in[4],
                                      d_in[5], d_in[6], d_in[7], d_in[8], d_in[9],
                                      flag, mode, canon, tabpj, rV, lsum);
    prep1_k<<<257, 256, 0, stream>>>(Wskc, Wzc, Wqc, Wkc, RPc, bqc, bskc, bzc,
                                     Wtcat, Wkr, bias);
    big_k<<<512, 512, 0, stream>>>(Xc, Wtcat, bias, skip, z, qs, E, lsum);
    router_v_k<<<dim3(16, 32), 256, 0, stream>>>(E, lsum, Xc, tabpj, rV);
    final_attn_k<<<dim3(64, 8, 4), 256, 0, stream>>>(qs, rV, tabpj, skip, z, flag,
                                                     mode, d_out);
}